// Round 4
// baseline (728.536 us; speedup 1.0000x reference)
//
#include <hip/hip_runtime.h>

#define NB 8192
#define NT 24

typedef float v2f __attribute__((ext_vector_type(2)));

__device__ __forceinline__ float rcp_fast(float x) { return __builtin_amdgcn_rcpf(x); }
__device__ __forceinline__ float sigmoid_f(float x) { return rcp_fast(1.f + __expf(-x)); }
__device__ __forceinline__ float tanh_f(float x) { return 1.f - 2.f * rcp_fast(1.f + __expf(2.f * x)); }
__device__ __forceinline__ v2f v2(float a, float b) { v2f r; r.x = a; r.y = b; return r; }
__device__ __forceinline__ v2f v2s(float a) { v2f r; r.x = a; r.y = a; return r; }
__device__ __forceinline__ v2f v2fma(v2f a, v2f b, v2f c) { return __builtin_elementwise_fma(a, b, c); }

// Full sum across the 16 contiguous lanes of a group (groups aligned to 16).
__device__ __forceinline__ float dpp16_sum(float x) {
  int v;
  v = __builtin_amdgcn_update_dpp(0, __float_as_int(x), 0xB1, 0xF, 0xF, true);  // quad_perm(1,0,3,2)
  x += __int_as_float(v);
  v = __builtin_amdgcn_update_dpp(0, __float_as_int(x), 0x4E, 0xF, 0xF, true);  // quad_perm(2,3,0,1)
  x += __int_as_float(v);
  v = __builtin_amdgcn_update_dpp(0, __float_as_int(x), 0x141, 0xF, 0xF, true); // ROW_HALF_MIRROR
  x += __int_as_float(v);
  v = __builtin_amdgcn_update_dpp(0, __float_as_int(x), 0x140, 0xF, 0xF, true); // ROW_MIRROR
  x += __int_as_float(v);
  return x;
}

// 3 packed gate accumulators vs [96][32] pair-interleaved tile (16 col-pairs/gate).
#define GATE_PK16(T, hq, kk, gr, gz, gn)                        \
  do {                                                          \
    const float4 a0 = T[(0 * 16 + 2 * (kk)) * 16 + jj];         \
    const float4 a1 = T[(0 * 16 + 2 * (kk) + 1) * 16 + jj];     \
    const float4 b0 = T[(1 * 16 + 2 * (kk)) * 16 + jj];         \
    const float4 b1 = T[(1 * 16 + 2 * (kk) + 1) * 16 + jj];     \
    const float4 c0 = T[(2 * 16 + 2 * (kk)) * 16 + jj];         \
    const float4 c1 = T[(2 * 16 + 2 * (kk) + 1) * 16 + jj];     \
    gr = v2fma(v2s(hq.x), v2(a0.x, a0.y), gr);                  \
    gr = v2fma(v2s(hq.y), v2(a0.z, a0.w), gr);                  \
    gr = v2fma(v2s(hq.z), v2(a1.x, a1.y), gr);                  \
    gr = v2fma(v2s(hq.w), v2(a1.z, a1.w), gr);                  \
    gz = v2fma(v2s(hq.x), v2(b0.x, b0.y), gz);                  \
    gz = v2fma(v2s(hq.y), v2(b0.z, b0.w), gz);                  \
    gz = v2fma(v2s(hq.z), v2(b1.x, b1.y), gz);                  \
    gz = v2fma(v2s(hq.w), v2(b1.z, b1.w), gz);                  \
    gn = v2fma(v2s(hq.x), v2(c0.x, c0.y), gn);                  \
    gn = v2fma(v2s(hq.y), v2(c0.z, c0.w), gn);                  \
    gn = v2fma(v2s(hq.z), v2(c1.x, c1.y), gn);                  \
    gn = v2fma(v2s(hq.w), v2(c1.z, c1.w), gn);                  \
  } while (0)

// Same but for the folded M tile [96][16] (8 col-pairs/gate).
#define GATE_PK8(T, hq, kk, gr, gz, gn)                         \
  do {                                                          \
    const float4 a0 = T[(0 * 8 + 2 * (kk)) * 16 + jj];          \
    const float4 a1 = T[(0 * 8 + 2 * (kk) + 1) * 16 + jj];      \
    const float4 b0 = T[(1 * 8 + 2 * (kk)) * 16 + jj];          \
    const float4 b1 = T[(1 * 8 + 2 * (kk) + 1) * 16 + jj];      \
    const float4 c0 = T[(2 * 8 + 2 * (kk)) * 16 + jj];          \
    const float4 c1 = T[(2 * 8 + 2 * (kk) + 1) * 16 + jj];      \
    gr = v2fma(v2s(hq.x), v2(a0.x, a0.y), gr);                  \
    gr = v2fma(v2s(hq.y), v2(a0.z, a0.w), gr);                  \
    gr = v2fma(v2s(hq.z), v2(a1.x, a1.y), gr);                  \
    gr = v2fma(v2s(hq.w), v2(a1.z, a1.w), gr);                  \
    gz = v2fma(v2s(hq.x), v2(b0.x, b0.y), gz);                  \
    gz = v2fma(v2s(hq.y), v2(b0.z, b0.w), gz);                  \
    gz = v2fma(v2s(hq.z), v2(b1.x, b1.y), gz);                  \
    gz = v2fma(v2s(hq.w), v2(b1.z, b1.w), gz);                  \
    gn = v2fma(v2s(hq.x), v2(c0.x, c0.y), gn);                  \
    gn = v2fma(v2s(hq.y), v2(c0.z, c0.w), gn);                  \
    gn = v2fma(v2s(hq.z), v2(c1.x, c1.y), gn);                  \
    gn = v2fma(v2s(hq.w), v2(c1.z, c1.w), gn);                  \
  } while (0)

__global__ __launch_bounds__(256, 2) void darnn_kernel(
    const float* __restrict__ x, const float* __restrict__ h0_enc, const float* __restrict__ h0_dec,
    const float* __restrict__ attn1_w, const float* __restrict__ attn1_b,
    const float* __restrict__ attn2_w, const float* __restrict__ attn2_b,
    const float* __restrict__ attn3_w, const float* __restrict__ attn3_b,
    const float* __restrict__ enc_wih, const float* __restrict__ enc_whh,
    const float* __restrict__ enc_bih, const float* __restrict__ enc_bhh,
    const float* __restrict__ l1_w, const float* __restrict__ l1_b,
    const float* __restrict__ l2_w, const float* __restrict__ l2_b,
    const float* __restrict__ l3_w, const float* __restrict__ l3_b,
    const float* __restrict__ l4_w, const float* __restrict__ l4_b,
    const float* __restrict__ dec_wih, const float* __restrict__ dec_whh,
    const float* __restrict__ dec_bih, const float* __restrict__ dec_bhh,
    const float* __restrict__ fc_w, const float* __restrict__ fc_b,
    float* __restrict__ out)
{
  __shared__ float4 s_dwhh4[768];   // 12 KB pair-interleaved dec_whh
  __shared__ float4 s_l1w4[256];    // 4 KB
  __shared__ float4 s_l2w4[128];    // 2 KB
  __shared__ float4 s_m4[384];      // 6 KB: M = dec_wih @ l4_w[:, :16]  (96x16) pair-interleaved
  __shared__ float4 s_cmx[96];      // 1.5 KB: {c0_r, MX_r0, MX_r1, MX_r2}
  __shared__ float4 s_x4[16][24];   // 6 KB
  __shared__ float s_bc[16][48];    // stride 48: groups 0,2 vs 1,3 split banks 0-15/16-31 (2-way = free)

  const int tid = threadIdx.x;
  const int g = tid >> 4;
  const int jj = tid & 15;
  const int b = blockIdx.x * 16 + g;
  const int j0 = jj, j1 = jj + 16;

  // ---- stage tiles ----
  for (int i = tid; i < 768; i += 256) {
    const int q = i >> 8, cp = (i >> 4) & 15, j = i & 15;
    const int r0 = q * 32 + j, r1 = r0 + 16, c0 = 2 * cp;
    float4 f;
    f.x = dec_whh[r0 * 32 + c0]; f.y = dec_whh[r1 * 32 + c0];
    f.z = dec_whh[r0 * 32 + c0 + 1]; f.w = dec_whh[r1 * 32 + c0 + 1];
    s_dwhh4[i] = f;
  }
  {
    const int cp = tid >> 4, j = tid & 15, c0 = 2 * cp;  // exactly 256
    float4 f;
    f.x = l1_w[j * 32 + c0]; f.y = l1_w[(j + 16) * 32 + c0];
    f.z = l1_w[j * 32 + c0 + 1]; f.w = l1_w[(j + 16) * 32 + c0 + 1];
    s_l1w4[tid] = f;
  }
  if (tid < 128) {
    const int cp = tid >> 4, j = tid & 15, c0 = 2 * cp;
    float4 e;
    e.x = l2_w[j * 16 + c0]; e.y = l2_w[(j + 16) * 16 + c0];
    e.z = l2_w[j * 16 + c0 + 1]; e.w = l2_w[(j + 16) * 16 + c0 + 1];
    s_l2w4[tid] = e;
  }
  // M = dec_wih @ l4_w[:, :16]  (pair-interleaved, 8 col-pairs per gate)
  for (int i = tid; i < 384; i += 256) {
    const int j = i & 15, t4 = i >> 4;
    const int q = t4 >> 3, cp = t4 & 7;
    const int r0 = q * 32 + j, r1 = r0 + 16, c0 = 2 * cp, c1 = c0 + 1;
    float4 f; f.x = 0.f; f.y = 0.f; f.z = 0.f; f.w = 0.f;
    for (int k = 0; k < 32; ++k) {
      const float w0 = dec_wih[r0 * 32 + k], w1 = dec_wih[r1 * 32 + k];
      const float lc0 = l4_w[k * 19 + c0], lc1 = l4_w[k * 19 + c1];
      f.x += w0 * lc0; f.y += w1 * lc0; f.z += w0 * lc1; f.w += w1 * lc1;
    }
    s_m4[i] = f;
  }
  // c0 = dec_bih + dec_wih @ l4_b ; MX = dec_wih @ l4_w[:, 16:19]
  for (int r = tid; r < 96; r += 256) {
    float c = dec_bih[r], m0 = 0.f, m1 = 0.f, m2 = 0.f;
    for (int k = 0; k < 32; ++k) {
      const float w = dec_wih[r * 32 + k];
      c += w * l4_b[k];
      m0 += w * l4_w[k * 19 + 16]; m1 += w * l4_w[k * 19 + 17]; m2 += w * l4_w[k * 19 + 18];
    }
    float4 f; f.x = c; f.y = m0; f.z = m1; f.w = m2;
    s_cmx[r] = f;
  }
  {
    const int b0 = blockIdx.x * 16;
    for (int i = tid; i < 16 * 24; i += 256) {
      const int gg = i / 24, tt = i - gg * 24;
      const float* src = x + (b0 + gg) * 72 + tt * 3;
      float4 f; f.x = src[0]; f.y = src[1]; f.z = src[2]; f.w = 0.f;
      s_x4[gg][tt] = f;
    }
  }
  __syncthreads();

  // ================= ENCODER (+ inline w2d) =================
  const float A1c0 = attn1_w[jj], A1c1 = attn1_w[16 + jj], A1c2 = attn1_w[32 + jj];
  const float a1b0 = attn1_b[0], a1b1 = attn1_b[1], a1b2 = attn1_b[2];
  float A2[9], A3[9];
#pragma unroll
  for (int i = 0; i < 9; ++i) { A2[i] = attn2_w[i]; A3[i] = attn3_w[i]; }
  const float a2b0 = attn2_b[0], a2b1 = attn2_b[1], a2b2 = attn2_b[2];
  const float a3b0 = attn3_b[0], a3b1 = attn3_b[1], a3b2 = attn3_b[2];
  float WI[3][3];
#pragma unroll
  for (int c = 0; c < 3; ++c)
#pragma unroll
    for (int i = 0; i < 3; ++i) WI[c][i] = enc_wih[(c * 16 + jj) * 3 + i];
  const float BI0 = enc_bih[jj], BI1 = enc_bih[16 + jj], BI2 = enc_bih[32 + jj];
  v2f WHr[8], WHz[8], WHn[8];
#pragma unroll
  for (int k = 0; k < 8; ++k) {
    WHr[k] = v2(enc_whh[jj * 16 + 2 * k], enc_whh[jj * 16 + 2 * k + 1]);
    WHz[k] = v2(enc_whh[(16 + jj) * 16 + 2 * k], enc_whh[(16 + jj) * 16 + 2 * k + 1]);
    WHn[k] = v2(enc_whh[(32 + jj) * 16 + 2 * k], enc_whh[(32 + jj) * 16 + 2 * k + 1]);
  }
  const float BH0 = enc_bhh[jj], BH1 = enc_bhh[16 + jj], BH2 = enc_bhh[32 + jj];
  const v2f l2bv = v2(l2_b[j0], l2_b[j1]);

  float h = h0_enc[b * 16 + jj];
  float enc_reg[NT];
  v2f w2dv[NT];

  s_bc[g][jj] = h;  // same-wave in-order DS: no fence needed

#pragma unroll
  for (int t = 0; t < NT; ++t) {
    const float4 xq = s_x4[g][t];
    const float xs0 = xq.x, xs1 = xq.y, xs2 = xq.z;
    // input-attention (3 independent dpp16 chains); softmax max-free (|v| bounded ~1.5)
    const float w10 = dpp16_sum(h * A1c0) + a1b0;
    const float w11 = dpp16_sum(h * A1c1) + a1b1;
    const float w12 = dpp16_sum(h * A1c2) + a1b2;
    const float w20 = a2b0 + xs0 * A2[0] + xs1 * A2[1] + xs2 * A2[2];
    const float w21 = a2b1 + xs0 * A2[3] + xs1 * A2[4] + xs2 * A2[5];
    const float w22 = a2b2 + xs0 * A2[6] + xs1 * A2[7] + xs2 * A2[8];
    const float t0 = tanh_f(w10 + w20), t1 = tanh_f(w11 + w21), t2 = tanh_f(w12 + w22);
    const float v0 = a3b0 + t0 * A3[0] + t1 * A3[1] + t2 * A3[2];
    const float v1 = a3b1 + t0 * A3[3] + t1 * A3[4] + t2 * A3[5];
    const float v2_ = a3b2 + t0 * A3[6] + t1 * A3[7] + t2 * A3[8];
    const float e0 = __expf(v0), e1 = __expf(v1), e2 = __expf(v2_);
    const float rs = rcp_fast(e0 + e1 + e2);
    const float wx0 = xs0 * e0 * rs, wx1 = xs1 * e1 * rs, wx2 = xs2 * e2 * rs;
    // GRU cell (packed whh)
    const float gir = BI0 + wx0 * WI[0][0] + wx1 * WI[0][1] + wx2 * WI[0][2];
    const float giz = BI1 + wx0 * WI[1][0] + wx1 * WI[1][1] + wx2 * WI[1][2];
    const float gin = BI2 + wx0 * WI[2][0] + wx1 * WI[2][1] + wx2 * WI[2][2];
    v2f ar = v2s(0.f), az = v2s(0.f), an = v2s(0.f);
#pragma unroll
    for (int kk = 0; kk < 4; ++kk) {
      const float4 hq = *(const float4*)&s_bc[g][4 * kk];
      const v2f hp0 = v2(hq.x, hq.y), hp1 = v2(hq.z, hq.w);
      ar = v2fma(hp0, WHr[2 * kk], ar); ar = v2fma(hp1, WHr[2 * kk + 1], ar);
      az = v2fma(hp0, WHz[2 * kk], az); az = v2fma(hp1, WHz[2 * kk + 1], az);
      an = v2fma(hp0, WHn[2 * kk], an); an = v2fma(hp1, WHn[2 * kk + 1], an);
    }
    const float ghr = BH0 + ar.x + ar.y;
    const float ghz = BH1 + az.x + az.y;
    const float ghn = BH2 + an.x + an.y;
    const float r = sigmoid_f(gir + ghr);
    const float z = sigmoid_f(giz + ghz);
    const float n = tanh_f(gin + r * ghn);
    h = (1.f - z) * n + z * h;
    enc_reg[t] = h;
    s_bc[g][jj] = h;
    // w2d[t] = l2(enc[t]) packed over (j0,j1)
    v2f w2t = l2bv;
#pragma unroll
    for (int kk = 0; kk < 4; ++kk) {
      const float4 hq = *(const float4*)&s_bc[g][4 * kk];
      const float4 f0 = s_l2w4[(2 * kk) * 16 + jj];
      const float4 f1 = s_l2w4[(2 * kk + 1) * 16 + jj];
      w2t = v2fma(v2s(hq.x), v2(f0.x, f0.y), w2t);
      w2t = v2fma(v2s(hq.y), v2(f0.z, f0.w), w2t);
      w2t = v2fma(v2s(hq.z), v2(f1.x, f1.y), w2t);
      w2t = v2fma(v2s(hq.w), v2(f1.z, f1.w), w2t);
    }
    w2dv[t] = w2t;
  }

  // ================= DECODER =================
  const v2f l1bv = v2(l1_b[j0], l1_b[j1]);
  const v2f l3v = v2(l3_w[j0], l3_w[j1]);
  const v2f dhrv = v2(dec_bhh[j0], dec_bhh[j1]);
  const v2f dhzv = v2(dec_bhh[32 + j0], dec_bhh[32 + j1]);
  const v2f dhnv = v2(dec_bhh[64 + j0], dec_bhh[64 + j1]);
  // folded gi constants: c0 + MX@x per gate
  const float4 cr0 = s_cmx[j0], cr1 = s_cmx[j1];
  const float4 cz0 = s_cmx[32 + j0], cz1 = s_cmx[32 + j1];
  const float4 cn0 = s_cmx[64 + j0], cn1 = s_cmx[64 + j1];
  const v2f crc = v2(cr0.x, cr1.x), crx0 = v2(cr0.y, cr1.y), crx1 = v2(cr0.z, cr1.z), crx2 = v2(cr0.w, cr1.w);
  const v2f czc = v2(cz0.x, cz1.x), czx0 = v2(cz0.y, cz1.y), czx1 = v2(cz0.z, cz1.z), czx2 = v2(cz0.w, cz1.w);
  const v2f cnc = v2(cn0.x, cn1.x), cnx0 = v2(cn0.y, cn1.y), cnx1 = v2(cn0.z, cn1.z), cnx2 = v2(cn0.w, cn1.w);

  float hd0 = h0_dec[b * 32 + j0], hd1 = h0_dec[b * 32 + j1];

  for (int t = 0; t < NT; ++t) {
    const float4 xq = s_x4[g][t];

    s_bc[g][jj] = hd0;
    s_bc[g][16 + jj] = hd1;

    // --- w1 = l1(hd) and gh = dec_whh @ hd (share hd broadcast quads) ---
    v2f w1v = l1bv;
    v2f hrv = dhrv, hzv = dhzv, hnv = dhnv;
#pragma unroll
    for (int kk = 0; kk < 8; ++kk) {
      const float4 hq = *(const float4*)&s_bc[g][4 * kk];
      const float4 f0 = s_l1w4[(2 * kk) * 16 + jj];
      const float4 f1 = s_l1w4[(2 * kk + 1) * 16 + jj];
      w1v = v2fma(v2s(hq.x), v2(f0.x, f0.y), w1v);
      w1v = v2fma(v2s(hq.y), v2(f0.z, f0.w), w1v);
      w1v = v2fma(v2s(hq.z), v2(f1.x, f1.y), w1v);
      w1v = v2fma(v2s(hq.w), v2(f1.z, f1.w), w1v);
      GATE_PK16(s_dwhh4, hq, kk, hrv, hzv, hnv);
    }

    // --- temporal attention: max-free online softmax (scores bounded by sum|l3| ~ 2.6) ---
    float ssum = 0.f, wcacc = 0.f;
#pragma unroll
    for (int ch = 0; ch < 6; ++ch) {
      float p[4];
#pragma unroll
      for (int u = 0; u < 4; ++u) {
        const v2f av = w1v + w2dv[4 * ch + u];
        p[u] = __expf(dpp16_sum(l3v.x * tanh_f(av.x) + l3v.y * tanh_f(av.y)));
      }
      ssum += (p[0] + p[1]) + (p[2] + p[3]);
      wcacc += (p[0] * enc_reg[4 * ch] + p[1] * enc_reg[4 * ch + 1]) +
               (p[2] * enc_reg[4 * ch + 2] + p[3] * enc_reg[4 * ch + 3]);
    }
    const float wc = wcacc * rcp_fast(ssum);

    // --- gi = c0 + MX@x + M@wc  (l4 folded into dec_wih) ---
    s_bc[g][jj] = wc;
    v2f irv = crc, izv = czc, inv = cnc;
    irv = v2fma(v2s(xq.x), crx0, irv); irv = v2fma(v2s(xq.y), crx1, irv); irv = v2fma(v2s(xq.z), crx2, irv);
    izv = v2fma(v2s(xq.x), czx0, izv); izv = v2fma(v2s(xq.y), czx1, izv); izv = v2fma(v2s(xq.z), czx2, izv);
    inv = v2fma(v2s(xq.x), cnx0, inv); inv = v2fma(v2s(xq.y), cnx1, inv); inv = v2fma(v2s(xq.z), cnx2, inv);
#pragma unroll
    for (int kk = 0; kk < 4; ++kk) {
      const float4 cq = *(const float4*)&s_bc[g][4 * kk];
      GATE_PK8(s_m4, cq, kk, irv, izv, inv);
    }

    const float r0 = sigmoid_f(irv.x + hrv.x), r1 = sigmoid_f(irv.y + hrv.y);
    const float z0 = sigmoid_f(izv.x + hzv.x), z1 = sigmoid_f(izv.y + hzv.y);
    const float n0 = tanh_f(inv.x + r0 * hnv.x), n1 = tanh_f(inv.y + r1 * hnv.y);
    hd0 = (1.f - z0) * n0 + z0 * hd0;
    hd1 = (1.f - z1) * n1 + z1 * hd1;
  }

  // ---- final fc ----
  const float p0 = dpp16_sum(hd0 * fc_w[jj] + hd1 * fc_w[16 + jj]) + fc_b[0];
  const float p1 = dpp16_sum(hd0 * fc_w[32 + jj] + hd1 * fc_w[48 + jj]) + fc_b[1];
  const float p2 = dpp16_sum(hd0 * fc_w[64 + jj] + hd1 * fc_w[80 + jj]) + fc_b[2];
  if (jj == 0) {
    out[b * 3 + 0] = p0;
    out[b * 3 + 1] = p1;
    out[b * 3 + 2] = p2;
  }
}

extern "C" void kernel_launch(void* const* d_in, const int* in_sizes, int n_in,
                              void* d_out, int out_size, void* d_ws, size_t ws_size,
                              hipStream_t stream) {
  const float* p[27];
  for (int i = 0; i < 27; ++i) p[i] = (const float*)d_in[i];
  darnn_kernel<<<NB / 16, 256, 0, stream>>>(
      p[0], p[1], p[2], p[3], p[4], p[5], p[6], p[7], p[8],
      p[9], p[10], p[11], p[12], p[13], p[14], p[15], p[16], p[17], p[18],
      p[19], p[20], p[21], p[22], p[23], p[24], p[25], p[26],
      (float*)d_out);
}

// Round 5
// 139.253 us; speedup vs baseline: 5.2318x; 5.2318x over previous
//
#include <hip/hip_runtime.h>

#define NB 8192
#define NT 24

typedef float v2f __attribute__((ext_vector_type(2)));

__device__ __forceinline__ float rcp_fast(float x) { return __builtin_amdgcn_rcpf(x); }
__device__ __forceinline__ float sigmoid_f(float x) { return rcp_fast(1.f + __expf(-x)); }
__device__ __forceinline__ float tanh_f(float x) { return 1.f - 2.f * rcp_fast(1.f + __expf(2.f * x)); }
// same-wave LDS ordering + (critically) a scheduling barrier that caps live ranges.
// R4 removed these and register pressure exploded into HBM scratch thrash (1.5 GB FETCH).
__device__ __forceinline__ void lds_fence() { asm volatile("s_waitcnt lgkmcnt(0)" ::: "memory"); }
__device__ __forceinline__ v2f v2(float a, float b) { v2f r; r.x = a; r.y = b; return r; }
__device__ __forceinline__ v2f v2s(float a) { v2f r; r.x = a; r.y = a; return r; }
__device__ __forceinline__ v2f v2fma(v2f a, v2f b, v2f c) { return __builtin_elementwise_fma(a, b, c); }

// Full sum across the 16 contiguous lanes of a group (groups aligned to 16).
__device__ __forceinline__ float dpp16_sum(float x) {
  int v;
  v = __builtin_amdgcn_update_dpp(0, __float_as_int(x), 0xB1, 0xF, 0xF, true);  // quad_perm(1,0,3,2)
  x += __int_as_float(v);
  v = __builtin_amdgcn_update_dpp(0, __float_as_int(x), 0x4E, 0xF, 0xF, true);  // quad_perm(2,3,0,1)
  x += __int_as_float(v);
  v = __builtin_amdgcn_update_dpp(0, __float_as_int(x), 0x141, 0xF, 0xF, true); // ROW_HALF_MIRROR
  x += __int_as_float(v);
  v = __builtin_amdgcn_update_dpp(0, __float_as_int(x), 0x140, 0xF, 0xF, true); // ROW_MIRROR
  x += __int_as_float(v);
  return x;
}

// 3 packed gate accumulators vs [96][32] pair-interleaved tile (16 col-pairs/gate).
#define GATE_PK16(T, hq, kk, gr, gz, gn)                        \
  do {                                                          \
    const float4 a0 = T[(0 * 16 + 2 * (kk)) * 16 + jj];         \
    const float4 a1 = T[(0 * 16 + 2 * (kk) + 1) * 16 + jj];     \
    const float4 b0 = T[(1 * 16 + 2 * (kk)) * 16 + jj];         \
    const float4 b1 = T[(1 * 16 + 2 * (kk) + 1) * 16 + jj];     \
    const float4 c0 = T[(2 * 16 + 2 * (kk)) * 16 + jj];         \
    const float4 c1 = T[(2 * 16 + 2 * (kk) + 1) * 16 + jj];     \
    gr = v2fma(v2s(hq.x), v2(a0.x, a0.y), gr);                  \
    gr = v2fma(v2s(hq.y), v2(a0.z, a0.w), gr);                  \
    gr = v2fma(v2s(hq.z), v2(a1.x, a1.y), gr);                  \
    gr = v2fma(v2s(hq.w), v2(a1.z, a1.w), gr);                  \
    gz = v2fma(v2s(hq.x), v2(b0.x, b0.y), gz);                  \
    gz = v2fma(v2s(hq.y), v2(b0.z, b0.w), gz);                  \
    gz = v2fma(v2s(hq.z), v2(b1.x, b1.y), gz);                  \
    gz = v2fma(v2s(hq.w), v2(b1.z, b1.w), gz);                  \
    gn = v2fma(v2s(hq.x), v2(c0.x, c0.y), gn);                  \
    gn = v2fma(v2s(hq.y), v2(c0.z, c0.w), gn);                  \
    gn = v2fma(v2s(hq.z), v2(c1.x, c1.y), gn);                  \
    gn = v2fma(v2s(hq.w), v2(c1.z, c1.w), gn);                  \
  } while (0)

// Same but for the folded M tile [96][16] (8 col-pairs/gate).
#define GATE_PK8(T, hq, kk, gr, gz, gn)                         \
  do {                                                          \
    const float4 a0 = T[(0 * 8 + 2 * (kk)) * 16 + jj];          \
    const float4 a1 = T[(0 * 8 + 2 * (kk) + 1) * 16 + jj];      \
    const float4 b0 = T[(1 * 8 + 2 * (kk)) * 16 + jj];          \
    const float4 b1 = T[(1 * 8 + 2 * (kk) + 1) * 16 + jj];      \
    const float4 c0 = T[(2 * 8 + 2 * (kk)) * 16 + jj];          \
    const float4 c1 = T[(2 * 8 + 2 * (kk) + 1) * 16 + jj];      \
    gr = v2fma(v2s(hq.x), v2(a0.x, a0.y), gr);                  \
    gr = v2fma(v2s(hq.y), v2(a0.z, a0.w), gr);                  \
    gr = v2fma(v2s(hq.z), v2(a1.x, a1.y), gr);                  \
    gr = v2fma(v2s(hq.w), v2(a1.z, a1.w), gr);                  \
    gz = v2fma(v2s(hq.x), v2(b0.x, b0.y), gz);                  \
    gz = v2fma(v2s(hq.y), v2(b0.z, b0.w), gz);                  \
    gz = v2fma(v2s(hq.z), v2(b1.x, b1.y), gz);                  \
    gz = v2fma(v2s(hq.w), v2(b1.z, b1.w), gz);                  \
    gn = v2fma(v2s(hq.x), v2(c0.x, c0.y), gn);                  \
    gn = v2fma(v2s(hq.y), v2(c0.z, c0.w), gn);                  \
    gn = v2fma(v2s(hq.z), v2(c1.x, c1.y), gn);                  \
    gn = v2fma(v2s(hq.w), v2(c1.z, c1.w), gn);                  \
  } while (0)

__global__ __launch_bounds__(256, 3) void darnn_kernel(
    const float* __restrict__ x, const float* __restrict__ h0_enc, const float* __restrict__ h0_dec,
    const float* __restrict__ attn1_w, const float* __restrict__ attn1_b,
    const float* __restrict__ attn2_w, const float* __restrict__ attn2_b,
    const float* __restrict__ attn3_w, const float* __restrict__ attn3_b,
    const float* __restrict__ enc_wih, const float* __restrict__ enc_whh,
    const float* __restrict__ enc_bih, const float* __restrict__ enc_bhh,
    const float* __restrict__ l1_w, const float* __restrict__ l1_b,
    const float* __restrict__ l2_w, const float* __restrict__ l2_b,
    const float* __restrict__ l3_w, const float* __restrict__ l3_b,
    const float* __restrict__ l4_w, const float* __restrict__ l4_b,
    const float* __restrict__ dec_wih, const float* __restrict__ dec_whh,
    const float* __restrict__ dec_bih, const float* __restrict__ dec_bhh,
    const float* __restrict__ fc_w, const float* __restrict__ fc_b,
    float* __restrict__ out)
{
  __shared__ float4 s_dwhh4[768];   // 12 KB pair-interleaved dec_whh
  __shared__ float4 s_l1w4[256];    // 4 KB
  __shared__ float4 s_l2w4[128];    // 2 KB
  __shared__ float4 s_m4[384];      // 6 KB: M = dec_wih @ l4_w[:, :16]  (96x16) pair-interleaved
  __shared__ float4 s_cmx[96];      // 1.5 KB: {c0_r, MX_r0, MX_r1, MX_r2}
  __shared__ float4 s_x4[16][24];   // 6 KB
  __shared__ float s_bc[16][48];    // stride 48: 2-way group aliasing only (free)

  const int tid = threadIdx.x;
  const int g = tid >> 4;
  const int jj = tid & 15;
  const int b = blockIdx.x * 16 + g;
  const int j0 = jj, j1 = jj + 16;

  // ---- stage tiles ----
  for (int i = tid; i < 768; i += 256) {
    const int q = i >> 8, cp = (i >> 4) & 15, j = i & 15;
    const int r0 = q * 32 + j, r1 = r0 + 16, c0 = 2 * cp;
    float4 f;
    f.x = dec_whh[r0 * 32 + c0]; f.y = dec_whh[r1 * 32 + c0];
    f.z = dec_whh[r0 * 32 + c0 + 1]; f.w = dec_whh[r1 * 32 + c0 + 1];
    s_dwhh4[i] = f;
  }
  {
    const int cp = tid >> 4, j = tid & 15, c0 = 2 * cp;  // exactly 256
    float4 f;
    f.x = l1_w[j * 32 + c0]; f.y = l1_w[(j + 16) * 32 + c0];
    f.z = l1_w[j * 32 + c0 + 1]; f.w = l1_w[(j + 16) * 32 + c0 + 1];
    s_l1w4[tid] = f;
  }
  if (tid < 128) {
    const int cp = tid >> 4, j = tid & 15, c0 = 2 * cp;
    float4 e;
    e.x = l2_w[j * 16 + c0]; e.y = l2_w[(j + 16) * 16 + c0];
    e.z = l2_w[j * 16 + c0 + 1]; e.w = l2_w[(j + 16) * 16 + c0 + 1];
    s_l2w4[tid] = e;
  }
  // M = dec_wih @ l4_w[:, :16]  (pair-interleaved, 8 col-pairs per gate)
  for (int i = tid; i < 384; i += 256) {
    const int j = i & 15, t4 = i >> 4;
    const int q = t4 >> 3, cp = t4 & 7;
    const int r0 = q * 32 + j, r1 = r0 + 16, c0 = 2 * cp, c1 = c0 + 1;
    float4 f; f.x = 0.f; f.y = 0.f; f.z = 0.f; f.w = 0.f;
    for (int k = 0; k < 32; ++k) {
      const float w0 = dec_wih[r0 * 32 + k], w1 = dec_wih[r1 * 32 + k];
      const float lc0 = l4_w[k * 19 + c0], lc1 = l4_w[k * 19 + c1];
      f.x += w0 * lc0; f.y += w1 * lc0; f.z += w0 * lc1; f.w += w1 * lc1;
    }
    s_m4[i] = f;
  }
  // c0 = dec_bih + dec_wih @ l4_b ; MX = dec_wih @ l4_w[:, 16:19]
  for (int r = tid; r < 96; r += 256) {
    float c = dec_bih[r], m0 = 0.f, m1 = 0.f, m2 = 0.f;
    for (int k = 0; k < 32; ++k) {
      const float w = dec_wih[r * 32 + k];
      c += w * l4_b[k];
      m0 += w * l4_w[k * 19 + 16]; m1 += w * l4_w[k * 19 + 17]; m2 += w * l4_w[k * 19 + 18];
    }
    float4 f; f.x = c; f.y = m0; f.z = m1; f.w = m2;
    s_cmx[r] = f;
  }
  {
    const int b0 = blockIdx.x * 16;
    for (int i = tid; i < 16 * 24; i += 256) {
      const int gg = i / 24, tt = i - gg * 24;
      const float* src = x + (b0 + gg) * 72 + tt * 3;
      float4 f; f.x = src[0]; f.y = src[1]; f.z = src[2]; f.w = 0.f;
      s_x4[gg][tt] = f;
    }
  }
  __syncthreads();

  // ================= ENCODER (+ inline w2d) =================
  const float A1c0 = attn1_w[jj], A1c1 = attn1_w[16 + jj], A1c2 = attn1_w[32 + jj];
  const float a1b0 = attn1_b[0], a1b1 = attn1_b[1], a1b2 = attn1_b[2];
  float A2[9], A3[9];
#pragma unroll
  for (int i = 0; i < 9; ++i) { A2[i] = attn2_w[i]; A3[i] = attn3_w[i]; }
  const float a2b0 = attn2_b[0], a2b1 = attn2_b[1], a2b2 = attn2_b[2];
  const float a3b0 = attn3_b[0], a3b1 = attn3_b[1], a3b2 = attn3_b[2];
  float WI[3][3];
#pragma unroll
  for (int c = 0; c < 3; ++c)
#pragma unroll
    for (int i = 0; i < 3; ++i) WI[c][i] = enc_wih[(c * 16 + jj) * 3 + i];
  const float BI0 = enc_bih[jj], BI1 = enc_bih[16 + jj], BI2 = enc_bih[32 + jj];
  v2f WHr[8], WHz[8], WHn[8];
#pragma unroll
  for (int k = 0; k < 8; ++k) {
    WHr[k] = v2(enc_whh[jj * 16 + 2 * k], enc_whh[jj * 16 + 2 * k + 1]);
    WHz[k] = v2(enc_whh[(16 + jj) * 16 + 2 * k], enc_whh[(16 + jj) * 16 + 2 * k + 1]);
    WHn[k] = v2(enc_whh[(32 + jj) * 16 + 2 * k], enc_whh[(32 + jj) * 16 + 2 * k + 1]);
  }
  const float BH0 = enc_bhh[jj], BH1 = enc_bhh[16 + jj], BH2 = enc_bhh[32 + jj];
  const v2f l2bv = v2(l2_b[j0], l2_b[j1]);

  float h = h0_enc[b * 16 + jj];
  float enc_reg[NT];
  v2f w2dv[NT];

  s_bc[g][jj] = h;
  lds_fence();

#pragma unroll
  for (int t = 0; t < NT; ++t) {
    const float4 xq = s_x4[g][t];
    const float xs0 = xq.x, xs1 = xq.y, xs2 = xq.z;
    // input-attention (3 independent dpp16 chains); max-free softmax (|v| bounded ~1.5)
    const float w10 = dpp16_sum(h * A1c0) + a1b0;
    const float w11 = dpp16_sum(h * A1c1) + a1b1;
    const float w12 = dpp16_sum(h * A1c2) + a1b2;
    const float w20 = a2b0 + xs0 * A2[0] + xs1 * A2[1] + xs2 * A2[2];
    const float w21 = a2b1 + xs0 * A2[3] + xs1 * A2[4] + xs2 * A2[5];
    const float w22 = a2b2 + xs0 * A2[6] + xs1 * A2[7] + xs2 * A2[8];
    const float t0 = tanh_f(w10 + w20), t1 = tanh_f(w11 + w21), t2 = tanh_f(w12 + w22);
    const float v0 = a3b0 + t0 * A3[0] + t1 * A3[1] + t2 * A3[2];
    const float v1 = a3b1 + t0 * A3[3] + t1 * A3[4] + t2 * A3[5];
    const float v2_ = a3b2 + t0 * A3[6] + t1 * A3[7] + t2 * A3[8];
    const float e0 = __expf(v0), e1 = __expf(v1), e2 = __expf(v2_);
    const float rs = rcp_fast(e0 + e1 + e2);
    const float wx0 = xs0 * e0 * rs, wx1 = xs1 * e1 * rs, wx2 = xs2 * e2 * rs;
    // GRU cell (packed whh), reads h_{t-1} broadcast from s_bc
    const float gir = BI0 + wx0 * WI[0][0] + wx1 * WI[0][1] + wx2 * WI[0][2];
    const float giz = BI1 + wx0 * WI[1][0] + wx1 * WI[1][1] + wx2 * WI[1][2];
    const float gin = BI2 + wx0 * WI[2][0] + wx1 * WI[2][1] + wx2 * WI[2][2];
    v2f ar = v2s(0.f), az = v2s(0.f), an = v2s(0.f);
#pragma unroll
    for (int kk = 0; kk < 4; ++kk) {
      const float4 hq = *(const float4*)&s_bc[g][4 * kk];
      const v2f hp0 = v2(hq.x, hq.y), hp1 = v2(hq.z, hq.w);
      ar = v2fma(hp0, WHr[2 * kk], ar); ar = v2fma(hp1, WHr[2 * kk + 1], ar);
      az = v2fma(hp0, WHz[2 * kk], az); az = v2fma(hp1, WHz[2 * kk + 1], az);
      an = v2fma(hp0, WHn[2 * kk], an); an = v2fma(hp1, WHn[2 * kk + 1], an);
    }
    const float ghr = BH0 + ar.x + ar.y;
    const float ghz = BH1 + az.x + az.y;
    const float ghn = BH2 + an.x + an.y;
    const float r = sigmoid_f(gir + ghr);
    const float z = sigmoid_f(giz + ghz);
    const float n = tanh_f(gin + r * ghn);
    h = (1.f - z) * n + z * h;
    enc_reg[t] = h;
    s_bc[g][jj] = h;
    lds_fence();
    // w2d[t] = l2(enc[t]) packed over (j0,j1)
    v2f w2t = l2bv;
#pragma unroll
    for (int kk = 0; kk < 4; ++kk) {
      const float4 hq = *(const float4*)&s_bc[g][4 * kk];
      const float4 f0 = s_l2w4[(2 * kk) * 16 + jj];
      const float4 f1 = s_l2w4[(2 * kk + 1) * 16 + jj];
      w2t = v2fma(v2s(hq.x), v2(f0.x, f0.y), w2t);
      w2t = v2fma(v2s(hq.y), v2(f0.z, f0.w), w2t);
      w2t = v2fma(v2s(hq.z), v2(f1.x, f1.y), w2t);
      w2t = v2fma(v2s(hq.w), v2(f1.z, f1.w), w2t);
    }
    w2dv[t] = w2t;
  }

  // ================= DECODER =================
  const v2f l1bv = v2(l1_b[j0], l1_b[j1]);
  const v2f l3v = v2(l3_w[j0], l3_w[j1]);
  const v2f dhrv = v2(dec_bhh[j0], dec_bhh[j1]);
  const v2f dhzv = v2(dec_bhh[32 + j0], dec_bhh[32 + j1]);
  const v2f dhnv = v2(dec_bhh[64 + j0], dec_bhh[64 + j1]);
  // folded gi constants: c0 + MX@x per gate
  const float4 cr0 = s_cmx[j0], cr1 = s_cmx[j1];
  const float4 cz0 = s_cmx[32 + j0], cz1 = s_cmx[32 + j1];
  const float4 cn0 = s_cmx[64 + j0], cn1 = s_cmx[64 + j1];
  const v2f crc = v2(cr0.x, cr1.x), crx0 = v2(cr0.y, cr1.y), crx1 = v2(cr0.z, cr1.z), crx2 = v2(cr0.w, cr1.w);
  const v2f czc = v2(cz0.x, cz1.x), czx0 = v2(cz0.y, cz1.y), czx1 = v2(cz0.z, cz1.z), czx2 = v2(cz0.w, cz1.w);
  const v2f cnc = v2(cn0.x, cn1.x), cnx0 = v2(cn0.y, cn1.y), cnx1 = v2(cn0.z, cn1.z), cnx2 = v2(cn0.w, cn1.w);

  float hd0 = h0_dec[b * 32 + j0], hd1 = h0_dec[b * 32 + j1];

  for (int t = 0; t < NT; ++t) {
    const float4 xq = s_x4[g][t];

    s_bc[g][jj] = hd0;
    s_bc[g][16 + jj] = hd1;
    lds_fence();

    // --- w1 = l1(hd) and gh = dec_whh @ hd (share hd broadcast quads) ---
    v2f w1v = l1bv;
    v2f hrv = dhrv, hzv = dhzv, hnv = dhnv;
#pragma unroll
    for (int kk = 0; kk < 8; ++kk) {
      const float4 hq = *(const float4*)&s_bc[g][4 * kk];
      const float4 f0 = s_l1w4[(2 * kk) * 16 + jj];
      const float4 f1 = s_l1w4[(2 * kk + 1) * 16 + jj];
      w1v = v2fma(v2s(hq.x), v2(f0.x, f0.y), w1v);
      w1v = v2fma(v2s(hq.y), v2(f0.z, f0.w), w1v);
      w1v = v2fma(v2s(hq.z), v2(f1.x, f1.y), w1v);
      w1v = v2fma(v2s(hq.w), v2(f1.z, f1.w), w1v);
      GATE_PK16(s_dwhh4, hq, kk, hrv, hzv, hnv);
    }

    // --- temporal attention: max-free online softmax (scores bounded by sum|l3| ~ 2.6) ---
    float ssum = 0.f, wcacc = 0.f;
#pragma unroll
    for (int ch = 0; ch < 6; ++ch) {
      float p[4];
#pragma unroll
      for (int u = 0; u < 4; ++u) {
        const v2f av = w1v + w2dv[4 * ch + u];
        p[u] = __expf(dpp16_sum(l3v.x * tanh_f(av.x) + l3v.y * tanh_f(av.y)));
      }
      ssum += (p[0] + p[1]) + (p[2] + p[3]);
      wcacc += (p[0] * enc_reg[4 * ch] + p[1] * enc_reg[4 * ch + 1]) +
               (p[2] * enc_reg[4 * ch + 2] + p[3] * enc_reg[4 * ch + 3]);
    }
    const float wc = wcacc * rcp_fast(ssum);

    // --- gi = c0 + MX@x + M@wc  (l4 folded into dec_wih) ---
    s_bc[g][jj] = wc;
    lds_fence();
    v2f irv = crc, izv = czc, inv = cnc;
    irv = v2fma(v2s(xq.x), crx0, irv); irv = v2fma(v2s(xq.y), crx1, irv); irv = v2fma(v2s(xq.z), crx2, irv);
    izv = v2fma(v2s(xq.x), czx0, izv); izv = v2fma(v2s(xq.y), czx1, izv); izv = v2fma(v2s(xq.z), czx2, izv);
    inv = v2fma(v2s(xq.x), cnx0, inv); inv = v2fma(v2s(xq.y), cnx1, inv); inv = v2fma(v2s(xq.z), cnx2, inv);
#pragma unroll
    for (int kk = 0; kk < 4; ++kk) {
      const float4 cq = *(const float4*)&s_bc[g][4 * kk];
      GATE_PK8(s_m4, cq, kk, irv, izv, inv);
    }

    const float r0 = sigmoid_f(irv.x + hrv.x), r1 = sigmoid_f(irv.y + hrv.y);
    const float z0 = sigmoid_f(izv.x + hzv.x), z1 = sigmoid_f(izv.y + hzv.y);
    const float n0 = tanh_f(inv.x + r0 * hnv.x), n1 = tanh_f(inv.y + r1 * hnv.y);
    hd0 = (1.f - z0) * n0 + z0 * hd0;
    hd1 = (1.f - z1) * n1 + z1 * hd1;
  }

  // ---- final fc ----
  const float p0 = dpp16_sum(hd0 * fc_w[jj] + hd1 * fc_w[16 + jj]) + fc_b[0];
  const float p1 = dpp16_sum(hd0 * fc_w[32 + jj] + hd1 * fc_w[48 + jj]) + fc_b[1];
  const float p2 = dpp16_sum(hd0 * fc_w[64 + jj] + hd1 * fc_w[80 + jj]) + fc_b[2];
  if (jj == 0) {
    out[b * 3 + 0] = p0;
    out[b * 3 + 1] = p1;
    out[b * 3 + 2] = p2;
  }
}

extern "C" void kernel_launch(void* const* d_in, const int* in_sizes, int n_in,
                              void* d_out, int out_size, void* d_ws, size_t ws_size,
                              hipStream_t stream) {
  const float* p[27];
  for (int i = 0; i < 27; ++i) p[i] = (const float*)d_in[i];
  darnn_kernel<<<NB / 16, 256, 0, stream>>>(
      p[0], p[1], p[2], p[3], p[4], p[5], p[6], p[7], p[8],
      p[9], p[10], p[11], p[12], p[13], p[14], p[15], p[16], p[17], p[18],
      p[19], p[20], p[21], p[22], p[23], p[24], p[25], p[26],
      (float*)d_out);
}

// Round 6
// 138.791 us; speedup vs baseline: 5.2491x; 1.0033x over previous
//
#include <hip/hip_runtime.h>

#define NB 8192
#define NT 24

typedef float v2f __attribute__((ext_vector_type(2)));

__device__ __forceinline__ float rcp_fast(float x) { return __builtin_amdgcn_rcpf(x); }
__device__ __forceinline__ float sigmoid_f(float x) { return rcp_fast(1.f + __expf(-x)); }
__device__ __forceinline__ float tanh_f(float x) { return 1.f - 2.f * rcp_fast(1.f + __expf(2.f * x)); }
// Compiler-only scheduling/live-range barrier. Same-wave DS ops are in-order
// (R4: zero hardware fences, absmax 0), so no s_waitcnt is needed for the
// s_bc write->read ordering. But WITHOUT a compiler barrier the scheduler
// hoists loads across the whole loop and VGPRs explode into scratch (R4:
// 1.5 GB FETCH). This keeps the regalloc chop at zero hardware cost.
__device__ __forceinline__ void creg_fence() { asm volatile("" ::: "memory"); }
__device__ __forceinline__ v2f v2(float a, float b) { v2f r; r.x = a; r.y = b; return r; }
__device__ __forceinline__ v2f v2s(float a) { v2f r; r.x = a; r.y = a; return r; }
__device__ __forceinline__ v2f v2fma(v2f a, v2f b, v2f c) { return __builtin_elementwise_fma(a, b, c); }

// Full sum across the 16 contiguous lanes of a group (groups aligned to 16).
__device__ __forceinline__ float dpp16_sum(float x) {
  int v;
  v = __builtin_amdgcn_update_dpp(0, __float_as_int(x), 0xB1, 0xF, 0xF, true);  // quad_perm(1,0,3,2)
  x += __int_as_float(v);
  v = __builtin_amdgcn_update_dpp(0, __float_as_int(x), 0x4E, 0xF, 0xF, true);  // quad_perm(2,3,0,1)
  x += __int_as_float(v);
  v = __builtin_amdgcn_update_dpp(0, __float_as_int(x), 0x141, 0xF, 0xF, true); // ROW_HALF_MIRROR
  x += __int_as_float(v);
  v = __builtin_amdgcn_update_dpp(0, __float_as_int(x), 0x140, 0xF, 0xF, true); // ROW_MIRROR
  x += __int_as_float(v);
  return x;
}

// 3 packed gate accumulators vs [96][32] pair-interleaved tile (16 col-pairs/gate).
#define GATE_PK16(T, hq, kk, gr, gz, gn)                        \
  do {                                                          \
    const float4 a0 = T[(0 * 16 + 2 * (kk)) * 16 + jj];         \
    const float4 a1 = T[(0 * 16 + 2 * (kk) + 1) * 16 + jj];     \
    const float4 b0 = T[(1 * 16 + 2 * (kk)) * 16 + jj];         \
    const float4 b1 = T[(1 * 16 + 2 * (kk) + 1) * 16 + jj];     \
    const float4 c0 = T[(2 * 16 + 2 * (kk)) * 16 + jj];         \
    const float4 c1 = T[(2 * 16 + 2 * (kk) + 1) * 16 + jj];     \
    gr = v2fma(v2s(hq.x), v2(a0.x, a0.y), gr);                  \
    gr = v2fma(v2s(hq.y), v2(a0.z, a0.w), gr);                  \
    gr = v2fma(v2s(hq.z), v2(a1.x, a1.y), gr);                  \
    gr = v2fma(v2s(hq.w), v2(a1.z, a1.w), gr);                  \
    gz = v2fma(v2s(hq.x), v2(b0.x, b0.y), gz);                  \
    gz = v2fma(v2s(hq.y), v2(b0.z, b0.w), gz);                  \
    gz = v2fma(v2s(hq.z), v2(b1.x, b1.y), gz);                  \
    gz = v2fma(v2s(hq.w), v2(b1.z, b1.w), gz);                  \
    gn = v2fma(v2s(hq.x), v2(c0.x, c0.y), gn);                  \
    gn = v2fma(v2s(hq.y), v2(c0.z, c0.w), gn);                  \
    gn = v2fma(v2s(hq.z), v2(c1.x, c1.y), gn);                  \
    gn = v2fma(v2s(hq.w), v2(c1.z, c1.w), gn);                  \
  } while (0)

// Same but for the folded M tile [96][16] (8 col-pairs/gate).
#define GATE_PK8(T, hq, kk, gr, gz, gn)                         \
  do {                                                          \
    const float4 a0 = T[(0 * 8 + 2 * (kk)) * 16 + jj];          \
    const float4 a1 = T[(0 * 8 + 2 * (kk) + 1) * 16 + jj];      \
    const float4 b0 = T[(1 * 8 + 2 * (kk)) * 16 + jj];          \
    const float4 b1 = T[(1 * 8 + 2 * (kk) + 1) * 16 + jj];      \
    const float4 c0 = T[(2 * 8 + 2 * (kk)) * 16 + jj];          \
    const float4 c1 = T[(2 * 8 + 2 * (kk) + 1) * 16 + jj];      \
    gr = v2fma(v2s(hq.x), v2(a0.x, a0.y), gr);                  \
    gr = v2fma(v2s(hq.y), v2(a0.z, a0.w), gr);                  \
    gr = v2fma(v2s(hq.z), v2(a1.x, a1.y), gr);                  \
    gr = v2fma(v2s(hq.w), v2(a1.z, a1.w), gr);                  \
    gz = v2fma(v2s(hq.x), v2(b0.x, b0.y), gz);                  \
    gz = v2fma(v2s(hq.y), v2(b0.z, b0.w), gz);                  \
    gz = v2fma(v2s(hq.z), v2(b1.x, b1.y), gz);                  \
    gz = v2fma(v2s(hq.w), v2(b1.z, b1.w), gz);                  \
    gn = v2fma(v2s(hq.x), v2(c0.x, c0.y), gn);                  \
    gn = v2fma(v2s(hq.y), v2(c0.z, c0.w), gn);                  \
    gn = v2fma(v2s(hq.z), v2(c1.x, c1.y), gn);                  \
    gn = v2fma(v2s(hq.w), v2(c1.z, c1.w), gn);                  \
  } while (0)

__global__ __launch_bounds__(256, 3) void darnn_kernel(
    const float* __restrict__ x, const float* __restrict__ h0_enc, const float* __restrict__ h0_dec,
    const float* __restrict__ attn1_w, const float* __restrict__ attn1_b,
    const float* __restrict__ attn2_w, const float* __restrict__ attn2_b,
    const float* __restrict__ attn3_w, const float* __restrict__ attn3_b,
    const float* __restrict__ enc_wih, const float* __restrict__ enc_whh,
    const float* __restrict__ enc_bih, const float* __restrict__ enc_bhh,
    const float* __restrict__ l1_w, const float* __restrict__ l1_b,
    const float* __restrict__ l2_w, const float* __restrict__ l2_b,
    const float* __restrict__ l3_w, const float* __restrict__ l3_b,
    const float* __restrict__ l4_w, const float* __restrict__ l4_b,
    const float* __restrict__ dec_wih, const float* __restrict__ dec_whh,
    const float* __restrict__ dec_bih, const float* __restrict__ dec_bhh,
    const float* __restrict__ fc_w, const float* __restrict__ fc_b,
    float* __restrict__ out)
{
  __shared__ float4 s_dwhh4[768];   // 12 KB pair-interleaved dec_whh
  __shared__ float4 s_l1w4[256];    // 4 KB
  __shared__ float4 s_l2w4[128];    // 2 KB
  __shared__ float4 s_m4[384];      // 6 KB: M = dec_wih @ l4_w[:, :16]  (96x16) pair-interleaved
  __shared__ float4 s_cmx[96];      // 1.5 KB: {c0_r, MX_r0, MX_r1, MX_r2}
  __shared__ float4 s_x4[16][24];   // 6 KB
  __shared__ float s_bc[16][48];    // stride 48: 2-way group aliasing only (free)

  const int tid = threadIdx.x;
  const int g = tid >> 4;
  const int jj = tid & 15;
  const int b = blockIdx.x * 16 + g;
  const int j0 = jj, j1 = jj + 16;

  // ---- stage tiles ----
  for (int i = tid; i < 768; i += 256) {
    const int q = i >> 8, cp = (i >> 4) & 15, j = i & 15;
    const int r0 = q * 32 + j, r1 = r0 + 16, c0 = 2 * cp;
    float4 f;
    f.x = dec_whh[r0 * 32 + c0]; f.y = dec_whh[r1 * 32 + c0];
    f.z = dec_whh[r0 * 32 + c0 + 1]; f.w = dec_whh[r1 * 32 + c0 + 1];
    s_dwhh4[i] = f;
  }
  {
    const int cp = tid >> 4, j = tid & 15, c0 = 2 * cp;  // exactly 256
    float4 f;
    f.x = l1_w[j * 32 + c0]; f.y = l1_w[(j + 16) * 32 + c0];
    f.z = l1_w[j * 32 + c0 + 1]; f.w = l1_w[(j + 16) * 32 + c0 + 1];
    s_l1w4[tid] = f;
  }
  if (tid < 128) {
    const int cp = tid >> 4, j = tid & 15, c0 = 2 * cp;
    float4 e;
    e.x = l2_w[j * 16 + c0]; e.y = l2_w[(j + 16) * 16 + c0];
    e.z = l2_w[j * 16 + c0 + 1]; e.w = l2_w[(j + 16) * 16 + c0 + 1];
    s_l2w4[tid] = e;
  }
  // M = dec_wih @ l4_w[:, :16]  (pair-interleaved, 8 col-pairs per gate)
  for (int i = tid; i < 384; i += 256) {
    const int j = i & 15, t4 = i >> 4;
    const int q = t4 >> 3, cp = t4 & 7;
    const int r0 = q * 32 + j, r1 = r0 + 16, c0 = 2 * cp, c1 = c0 + 1;
    float4 f; f.x = 0.f; f.y = 0.f; f.z = 0.f; f.w = 0.f;
    for (int k = 0; k < 32; ++k) {
      const float w0 = dec_wih[r0 * 32 + k], w1 = dec_wih[r1 * 32 + k];
      const float lc0 = l4_w[k * 19 + c0], lc1 = l4_w[k * 19 + c1];
      f.x += w0 * lc0; f.y += w1 * lc0; f.z += w0 * lc1; f.w += w1 * lc1;
    }
    s_m4[i] = f;
  }
  // c0 = dec_bih + dec_wih @ l4_b ; MX = dec_wih @ l4_w[:, 16:19]
  for (int r = tid; r < 96; r += 256) {
    float c = dec_bih[r], m0 = 0.f, m1 = 0.f, m2 = 0.f;
    for (int k = 0; k < 32; ++k) {
      const float w = dec_wih[r * 32 + k];
      c += w * l4_b[k];
      m0 += w * l4_w[k * 19 + 16]; m1 += w * l4_w[k * 19 + 17]; m2 += w * l4_w[k * 19 + 18];
    }
    float4 f; f.x = c; f.y = m0; f.z = m1; f.w = m2;
    s_cmx[r] = f;
  }
  {
    const int b0 = blockIdx.x * 16;
    for (int i = tid; i < 16 * 24; i += 256) {
      const int gg = i / 24, tt = i - gg * 24;
      const float* src = x + (b0 + gg) * 72 + tt * 3;
      float4 f; f.x = src[0]; f.y = src[1]; f.z = src[2]; f.w = 0.f;
      s_x4[gg][tt] = f;
    }
  }
  __syncthreads();

  // ================= ENCODER (+ inline w2d) =================
  const float A1c0 = attn1_w[jj], A1c1 = attn1_w[16 + jj], A1c2 = attn1_w[32 + jj];
  const float a1b0 = attn1_b[0], a1b1 = attn1_b[1], a1b2 = attn1_b[2];
  float A2[9], A3[9];
#pragma unroll
  for (int i = 0; i < 9; ++i) { A2[i] = attn2_w[i]; A3[i] = attn3_w[i]; }
  const float a2b0 = attn2_b[0], a2b1 = attn2_b[1], a2b2 = attn2_b[2];
  const float a3b0 = attn3_b[0], a3b1 = attn3_b[1], a3b2 = attn3_b[2];
  float WI[3][3];
#pragma unroll
  for (int c = 0; c < 3; ++c)
#pragma unroll
    for (int i = 0; i < 3; ++i) WI[c][i] = enc_wih[(c * 16 + jj) * 3 + i];
  const float BI0 = enc_bih[jj], BI1 = enc_bih[16 + jj], BI2 = enc_bih[32 + jj];
  v2f WHr[8], WHz[8], WHn[8];
#pragma unroll
  for (int k = 0; k < 8; ++k) {
    WHr[k] = v2(enc_whh[jj * 16 + 2 * k], enc_whh[jj * 16 + 2 * k + 1]);
    WHz[k] = v2(enc_whh[(16 + jj) * 16 + 2 * k], enc_whh[(16 + jj) * 16 + 2 * k + 1]);
    WHn[k] = v2(enc_whh[(32 + jj) * 16 + 2 * k], enc_whh[(32 + jj) * 16 + 2 * k + 1]);
  }
  const float BH0 = enc_bhh[jj], BH1 = enc_bhh[16 + jj], BH2 = enc_bhh[32 + jj];
  const v2f l2bv = v2(l2_b[j0], l2_b[j1]);

  float h = h0_enc[b * 16 + jj];
  float enc_reg[NT];
  v2f w2dv[NT];

  s_bc[g][jj] = h;
  creg_fence();

#pragma unroll
  for (int t = 0; t < NT; ++t) {
    const float4 xq = s_x4[g][t];
    const float xs0 = xq.x, xs1 = xq.y, xs2 = xq.z;
    // input-attention (3 independent dpp16 chains); max-free softmax (|v| bounded ~1.5)
    const float w10 = dpp16_sum(h * A1c0) + a1b0;
    const float w11 = dpp16_sum(h * A1c1) + a1b1;
    const float w12 = dpp16_sum(h * A1c2) + a1b2;
    const float w20 = a2b0 + xs0 * A2[0] + xs1 * A2[1] + xs2 * A2[2];
    const float w21 = a2b1 + xs0 * A2[3] + xs1 * A2[4] + xs2 * A2[5];
    const float w22 = a2b2 + xs0 * A2[6] + xs1 * A2[7] + xs2 * A2[8];
    const float t0 = tanh_f(w10 + w20), t1 = tanh_f(w11 + w21), t2 = tanh_f(w12 + w22);
    const float v0 = a3b0 + t0 * A3[0] + t1 * A3[1] + t2 * A3[2];
    const float v1 = a3b1 + t0 * A3[3] + t1 * A3[4] + t2 * A3[5];
    const float v2_ = a3b2 + t0 * A3[6] + t1 * A3[7] + t2 * A3[8];
    const float e0 = __expf(v0), e1 = __expf(v1), e2 = __expf(v2_);
    const float rs = rcp_fast(e0 + e1 + e2);
    const float wx0 = xs0 * e0 * rs, wx1 = xs1 * e1 * rs, wx2 = xs2 * e2 * rs;
    // GRU cell (packed whh), reads h_{t-1} broadcast from s_bc
    const float gir = BI0 + wx0 * WI[0][0] + wx1 * WI[0][1] + wx2 * WI[0][2];
    const float giz = BI1 + wx0 * WI[1][0] + wx1 * WI[1][1] + wx2 * WI[1][2];
    const float gin = BI2 + wx0 * WI[2][0] + wx1 * WI[2][1] + wx2 * WI[2][2];
    v2f ar = v2s(0.f), az = v2s(0.f), an = v2s(0.f);
#pragma unroll
    for (int kk = 0; kk < 4; ++kk) {
      const float4 hq = *(const float4*)&s_bc[g][4 * kk];
      const v2f hp0 = v2(hq.x, hq.y), hp1 = v2(hq.z, hq.w);
      ar = v2fma(hp0, WHr[2 * kk], ar); ar = v2fma(hp1, WHr[2 * kk + 1], ar);
      az = v2fma(hp0, WHz[2 * kk], az); az = v2fma(hp1, WHz[2 * kk + 1], az);
      an = v2fma(hp0, WHn[2 * kk], an); an = v2fma(hp1, WHn[2 * kk + 1], an);
    }
    const float ghr = BH0 + ar.x + ar.y;
    const float ghz = BH1 + az.x + az.y;
    const float ghn = BH2 + an.x + an.y;
    const float r = sigmoid_f(gir + ghr);
    const float z = sigmoid_f(giz + ghz);
    const float n = tanh_f(gin + r * ghn);
    h = (1.f - z) * n + z * h;
    enc_reg[t] = h;
    s_bc[g][jj] = h;
    creg_fence();
    // w2d[t] = l2(enc[t]) packed over (j0,j1)
    v2f w2t = l2bv;
#pragma unroll
    for (int kk = 0; kk < 4; ++kk) {
      const float4 hq = *(const float4*)&s_bc[g][4 * kk];
      const float4 f0 = s_l2w4[(2 * kk) * 16 + jj];
      const float4 f1 = s_l2w4[(2 * kk + 1) * 16 + jj];
      w2t = v2fma(v2s(hq.x), v2(f0.x, f0.y), w2t);
      w2t = v2fma(v2s(hq.y), v2(f0.z, f0.w), w2t);
      w2t = v2fma(v2s(hq.z), v2(f1.x, f1.y), w2t);
      w2t = v2fma(v2s(hq.w), v2(f1.z, f1.w), w2t);
    }
    w2dv[t] = w2t;
  }

  // ================= DECODER =================
  const v2f l1bv = v2(l1_b[j0], l1_b[j1]);
  const v2f l3v = v2(l3_w[j0], l3_w[j1]);
  const v2f dhrv = v2(dec_bhh[j0], dec_bhh[j1]);
  const v2f dhzv = v2(dec_bhh[32 + j0], dec_bhh[32 + j1]);
  const v2f dhnv = v2(dec_bhh[64 + j0], dec_bhh[64 + j1]);
  // folded gi constants: c0 + MX@x per gate
  const float4 cr0 = s_cmx[j0], cr1 = s_cmx[j1];
  const float4 cz0 = s_cmx[32 + j0], cz1 = s_cmx[32 + j1];
  const float4 cn0 = s_cmx[64 + j0], cn1 = s_cmx[64 + j1];
  const v2f crc = v2(cr0.x, cr1.x), crx0 = v2(cr0.y, cr1.y), crx1 = v2(cr0.z, cr1.z), crx2 = v2(cr0.w, cr1.w);
  const v2f czc = v2(cz0.x, cz1.x), czx0 = v2(cz0.y, cz1.y), czx1 = v2(cz0.z, cz1.z), czx2 = v2(cz0.w, cz1.w);
  const v2f cnc = v2(cn0.x, cn1.x), cnx0 = v2(cn0.y, cn1.y), cnx1 = v2(cn0.z, cn1.z), cnx2 = v2(cn0.w, cn1.w);

  float hd0 = h0_dec[b * 32 + j0], hd1 = h0_dec[b * 32 + j1];

  for (int t = 0; t < NT; ++t) {
    const float4 xq = s_x4[g][t];

    s_bc[g][jj] = hd0;
    s_bc[g][16 + jj] = hd1;
    creg_fence();

    // --- w1 = l1(hd) and gh = dec_whh @ hd (share hd broadcast quads) ---
    v2f w1v = l1bv;
    v2f hrv = dhrv, hzv = dhzv, hnv = dhnv;
#pragma unroll
    for (int kk = 0; kk < 8; ++kk) {
      const float4 hq = *(const float4*)&s_bc[g][4 * kk];
      const float4 f0 = s_l1w4[(2 * kk) * 16 + jj];
      const float4 f1 = s_l1w4[(2 * kk + 1) * 16 + jj];
      w1v = v2fma(v2s(hq.x), v2(f0.x, f0.y), w1v);
      w1v = v2fma(v2s(hq.y), v2(f0.z, f0.w), w1v);
      w1v = v2fma(v2s(hq.z), v2(f1.x, f1.y), w1v);
      w1v = v2fma(v2s(hq.w), v2(f1.z, f1.w), w1v);
      GATE_PK16(s_dwhh4, hq, kk, hrv, hzv, hnv);
    }

    // --- temporal attention: max-free online softmax (scores bounded by sum|l3| ~ 2.6),
    //     2-way split accumulators to halve the serial fma chains ---
    float ssum0 = 0.f, ssum1 = 0.f, wca0 = 0.f, wca1 = 0.f;
#pragma unroll
    for (int ch = 0; ch < 6; ++ch) {
      float p[4];
#pragma unroll
      for (int u = 0; u < 4; ++u) {
        const v2f av = w1v + w2dv[4 * ch + u];
        p[u] = __expf(dpp16_sum(l3v.x * tanh_f(av.x) + l3v.y * tanh_f(av.y)));
      }
      ssum0 += p[0] + p[1];
      ssum1 += p[2] + p[3];
      wca0 += p[0] * enc_reg[4 * ch] + p[1] * enc_reg[4 * ch + 1];
      wca1 += p[2] * enc_reg[4 * ch + 2] + p[3] * enc_reg[4 * ch + 3];
    }
    const float wc = (wca0 + wca1) * rcp_fast(ssum0 + ssum1);

    // --- gi = c0 + MX@x + M@wc  (l4 folded into dec_wih) ---
    s_bc[g][jj] = wc;
    creg_fence();
    v2f irv = crc, izv = czc, inv = cnc;
    irv = v2fma(v2s(xq.x), crx0, irv); irv = v2fma(v2s(xq.y), crx1, irv); irv = v2fma(v2s(xq.z), crx2, irv);
    izv = v2fma(v2s(xq.x), czx0, izv); izv = v2fma(v2s(xq.y), czx1, izv); izv = v2fma(v2s(xq.z), czx2, izv);
    inv = v2fma(v2s(xq.x), cnx0, inv); inv = v2fma(v2s(xq.y), cnx1, inv); inv = v2fma(v2s(xq.z), cnx2, inv);
#pragma unroll
    for (int kk = 0; kk < 4; ++kk) {
      const float4 cq = *(const float4*)&s_bc[g][4 * kk];
      GATE_PK8(s_m4, cq, kk, irv, izv, inv);
    }

    const float r0 = sigmoid_f(irv.x + hrv.x), r1 = sigmoid_f(irv.y + hrv.y);
    const float z0 = sigmoid_f(izv.x + hzv.x), z1 = sigmoid_f(izv.y + hzv.y);
    const float n0 = tanh_f(inv.x + r0 * hnv.x), n1 = tanh_f(inv.y + r1 * hnv.y);
    hd0 = (1.f - z0) * n0 + z0 * hd0;
    hd1 = (1.f - z1) * n1 + z1 * hd1;
  }

  // ---- final fc ----
  const float p0 = dpp16_sum(hd0 * fc_w[jj] + hd1 * fc_w[16 + jj]) + fc_b[0];
  const float p1 = dpp16_sum(hd0 * fc_w[32 + jj] + hd1 * fc_w[48 + jj]) + fc_b[1];
  const float p2 = dpp16_sum(hd0 * fc_w[64 + jj] + hd1 * fc_w[80 + jj]) + fc_b[2];
  if (jj == 0) {
    out[b * 3 + 0] = p0;
    out[b * 3 + 1] = p1;
    out[b * 3 + 2] = p2;
  }
}

extern "C" void kernel_launch(void* const* d_in, const int* in_sizes, int n_in,
                              void* d_out, int out_size, void* d_ws, size_t ws_size,
                              hipStream_t stream) {
  const float* p[27];
  for (int i = 0; i < 27; ++i) p[i] = (const float*)d_in[i];
  darnn_kernel<<<NB / 16, 256, 0, stream>>>(
      p[0], p[1], p[2], p[3], p[4], p[5], p[6], p[7], p[8],
      p[9], p[10], p[11], p[12], p[13], p[14], p[15], p[16], p[17], p[18],
      p[19], p[20], p[21], p[22], p[23], p[24], p[25], p[26],
      (float*)d_out);
}

// Round 7
// 122.126 us; speedup vs baseline: 5.9655x; 1.1365x over previous
//
#include <hip/hip_runtime.h>

#define NB 8192
#define NT 24

typedef float v2f __attribute__((ext_vector_type(2)));

#define K2L 2.8853900817779268f  // 2*log2(e)
#define L2E 1.4426950408889634f  // log2(e)

__device__ __forceinline__ float rcp_fast(float x) { return __builtin_amdgcn_rcpf(x); }
__device__ __forceinline__ float exp2_fast(float x) { return __builtin_amdgcn_exp2f(x); }
__device__ __forceinline__ float sigmoid_f(float x) { return rcp_fast(1.f + exp2_fast(-L2E * x)); }
__device__ __forceinline__ float tanh_f(float x) { return 1.f - 2.f * rcp_fast(1.f + exp2_fast(K2L * x)); }
// Compiler-only scheduling/live-range barrier (R4: removing it exploded regs into
// scratch; R6: hardware drain vs this = identical perf, so keep the free version).
__device__ __forceinline__ void creg_fence() { asm volatile("" ::: "memory"); }
__device__ __forceinline__ v2f v2(float a, float b) { v2f r; r.x = a; r.y = b; return r; }
__device__ __forceinline__ v2f v2s(float a) { v2f r; r.x = a; r.y = a; return r; }
__device__ __forceinline__ v2f v2fma(v2f a, v2f b, v2f c) { return __builtin_elementwise_fma(a, b, c); }

// Full sum across the 16 contiguous lanes of a group (groups aligned to 16).
__device__ __forceinline__ float dpp16_sum(float x) {
  int v;
  v = __builtin_amdgcn_update_dpp(0, __float_as_int(x), 0xB1, 0xF, 0xF, true);  // quad_perm(1,0,3,2)
  x += __int_as_float(v);
  v = __builtin_amdgcn_update_dpp(0, __float_as_int(x), 0x4E, 0xF, 0xF, true);  // quad_perm(2,3,0,1)
  x += __int_as_float(v);
  v = __builtin_amdgcn_update_dpp(0, __float_as_int(x), 0x141, 0xF, 0xF, true); // ROW_HALF_MIRROR
  x += __int_as_float(v);
  v = __builtin_amdgcn_update_dpp(0, __float_as_int(x), 0x140, 0xF, 0xF, true); // ROW_MIRROR
  x += __int_as_float(v);
  return x;
}

// 3 packed gate accumulators vs [96][32] pair-interleaved LDS tile (16 col-pairs/gate).
#define GATE_PK16(T, hq, kk, gr, gz, gn)                        \
  do {                                                          \
    const float4 a0 = T[(0 * 16 + 2 * (kk)) * 16 + jj];         \
    const float4 a1 = T[(0 * 16 + 2 * (kk) + 1) * 16 + jj];     \
    const float4 b0 = T[(1 * 16 + 2 * (kk)) * 16 + jj];         \
    const float4 b1 = T[(1 * 16 + 2 * (kk) + 1) * 16 + jj];     \
    const float4 c0 = T[(2 * 16 + 2 * (kk)) * 16 + jj];         \
    const float4 c1 = T[(2 * 16 + 2 * (kk) + 1) * 16 + jj];     \
    gr = v2fma(v2s(hq.x), v2(a0.x, a0.y), gr);                  \
    gr = v2fma(v2s(hq.y), v2(a0.z, a0.w), gr);                  \
    gr = v2fma(v2s(hq.z), v2(a1.x, a1.y), gr);                  \
    gr = v2fma(v2s(hq.w), v2(a1.z, a1.w), gr);                  \
    gz = v2fma(v2s(hq.x), v2(b0.x, b0.y), gz);                  \
    gz = v2fma(v2s(hq.y), v2(b0.z, b0.w), gz);                  \
    gz = v2fma(v2s(hq.z), v2(b1.x, b1.y), gz);                  \
    gz = v2fma(v2s(hq.w), v2(b1.z, b1.w), gz);                  \
    gn = v2fma(v2s(hq.x), v2(c0.x, c0.y), gn);                  \
    gn = v2fma(v2s(hq.y), v2(c0.z, c0.w), gn);                  \
    gn = v2fma(v2s(hq.z), v2(c1.x, c1.y), gn);                  \
    gn = v2fma(v2s(hq.w), v2(c1.z, c1.w), gn);                  \
  } while (0)

// Folded-M gate block from REGISTER tile rm[24] (gate*8 + 2kk layout).
#define GATE_PK8R(hq, kk, gr, gz, gn)                           \
  do {                                                          \
    const float4 a0 = rm[0 * 8 + 2 * (kk)];                     \
    const float4 a1 = rm[0 * 8 + 2 * (kk) + 1];                 \
    const float4 b0 = rm[1 * 8 + 2 * (kk)];                     \
    const float4 b1 = rm[1 * 8 + 2 * (kk) + 1];                 \
    const float4 c0 = rm[2 * 8 + 2 * (kk)];                     \
    const float4 c1 = rm[2 * 8 + 2 * (kk) + 1];                 \
    gr = v2fma(v2s(hq.x), v2(a0.x, a0.y), gr);                  \
    gr = v2fma(v2s(hq.y), v2(a0.z, a0.w), gr);                  \
    gr = v2fma(v2s(hq.z), v2(a1.x, a1.y), gr);                  \
    gr = v2fma(v2s(hq.w), v2(a1.z, a1.w), gr);                  \
    gz = v2fma(v2s(hq.x), v2(b0.x, b0.y), gz);                  \
    gz = v2fma(v2s(hq.y), v2(b0.z, b0.w), gz);                  \
    gz = v2fma(v2s(hq.z), v2(b1.x, b1.y), gz);                  \
    gz = v2fma(v2s(hq.w), v2(b1.z, b1.w), gz);                  \
    gn = v2fma(v2s(hq.x), v2(c0.x, c0.y), gn);                  \
    gn = v2fma(v2s(hq.y), v2(c0.z, c0.w), gn);                  \
    gn = v2fma(v2s(hq.z), v2(c1.x, c1.y), gn);                  \
    gn = v2fma(v2s(hq.w), v2(c1.z, c1.w), gn);                  \
  } while (0)

__global__ __launch_bounds__(256, 2) void darnn_kernel(
    const float* __restrict__ x, const float* __restrict__ h0_enc, const float* __restrict__ h0_dec,
    const float* __restrict__ attn1_w, const float* __restrict__ attn1_b,
    const float* __restrict__ attn2_w, const float* __restrict__ attn2_b,
    const float* __restrict__ attn3_w, const float* __restrict__ attn3_b,
    const float* __restrict__ enc_wih, const float* __restrict__ enc_whh,
    const float* __restrict__ enc_bih, const float* __restrict__ enc_bhh,
    const float* __restrict__ l1_w, const float* __restrict__ l1_b,
    const float* __restrict__ l2_w, const float* __restrict__ l2_b,
    const float* __restrict__ l3_w, const float* __restrict__ l3_b,
    const float* __restrict__ l4_w, const float* __restrict__ l4_b,
    const float* __restrict__ dec_wih, const float* __restrict__ dec_whh,
    const float* __restrict__ dec_bih, const float* __restrict__ dec_bhh,
    const float* __restrict__ fc_w, const float* __restrict__ fc_b,
    float* __restrict__ out)
{
  __shared__ float4 s_dwhh4[768];   // 12 KB pair-interleaved dec_whh
  __shared__ float4 s_l1w4[256];    // 4 KB, pre-scaled by K2L (feeds attention only)
  __shared__ float4 s_l2w4[128];    // 2 KB, pre-scaled by K2L
  __shared__ float4 s_m4[384];      // 6 KB staging for register M-tile
  __shared__ float4 s_cmx[96];      // 1.5 KB: {c0_r, MX_r0, MX_r1, MX_r2}
  __shared__ float4 s_x4[16][24];   // 6 KB
  __shared__ float s_bc[16][48];    // broadcast buffer, stride 48

  const int tid = threadIdx.x;
  const int g = tid >> 4;
  const int jj = tid & 15;
  const int b = blockIdx.x * 16 + g;
  const int j0 = jj, j1 = jj + 16;

  // ---- stage tiles ----
  for (int i = tid; i < 768; i += 256) {
    const int q = i >> 8, cp = (i >> 4) & 15, j = i & 15;
    const int r0 = q * 32 + j, r1 = r0 + 16, c0 = 2 * cp;
    float4 f;
    f.x = dec_whh[r0 * 32 + c0]; f.y = dec_whh[r1 * 32 + c0];
    f.z = dec_whh[r0 * 32 + c0 + 1]; f.w = dec_whh[r1 * 32 + c0 + 1];
    s_dwhh4[i] = f;
  }
  {
    const int cp = tid >> 4, j = tid & 15, c0 = 2 * cp;  // exactly 256
    float4 f;  // K2L-prescaled: w1 comes out in exp2 units
    f.x = K2L * l1_w[j * 32 + c0]; f.y = K2L * l1_w[(j + 16) * 32 + c0];
    f.z = K2L * l1_w[j * 32 + c0 + 1]; f.w = K2L * l1_w[(j + 16) * 32 + c0 + 1];
    s_l1w4[tid] = f;
  }
  if (tid < 128) {
    const int cp = tid >> 4, j = tid & 15, c0 = 2 * cp;
    float4 e;  // K2L-prescaled: w2d in exp2 units
    e.x = K2L * l2_w[j * 16 + c0]; e.y = K2L * l2_w[(j + 16) * 16 + c0];
    e.z = K2L * l2_w[j * 16 + c0 + 1]; e.w = K2L * l2_w[(j + 16) * 16 + c0 + 1];
    s_l2w4[tid] = e;
  }
  // M = dec_wih @ l4_w[:, :16]  (pair-interleaved, 8 col-pairs per gate)
  for (int i = tid; i < 384; i += 256) {
    const int j = i & 15, t4 = i >> 4;
    const int q = t4 >> 3, cp = t4 & 7;
    const int r0 = q * 32 + j, r1 = r0 + 16, c0 = 2 * cp, c1 = c0 + 1;
    float4 f; f.x = 0.f; f.y = 0.f; f.z = 0.f; f.w = 0.f;
    for (int k = 0; k < 32; ++k) {
      const float w0 = dec_wih[r0 * 32 + k], w1 = dec_wih[r1 * 32 + k];
      const float lc0 = l4_w[k * 19 + c0], lc1 = l4_w[k * 19 + c1];
      f.x += w0 * lc0; f.y += w1 * lc0; f.z += w0 * lc1; f.w += w1 * lc1;
    }
    s_m4[i] = f;
  }
  // c0 = dec_bih + dec_wih @ l4_b ; MX = dec_wih @ l4_w[:, 16:19]
  for (int r = tid; r < 96; r += 256) {
    float c = dec_bih[r], m0 = 0.f, m1 = 0.f, m2 = 0.f;
    for (int k = 0; k < 32; ++k) {
      const float w = dec_wih[r * 32 + k];
      c += w * l4_b[k];
      m0 += w * l4_w[k * 19 + 16]; m1 += w * l4_w[k * 19 + 17]; m2 += w * l4_w[k * 19 + 18];
    }
    float4 f; f.x = c; f.y = m0; f.z = m1; f.w = m2;
    s_cmx[r] = f;
  }
  {
    const int b0 = blockIdx.x * 16;
    for (int i = tid; i < 16 * 24; i += 256) {
      const int gg = i / 24, tt = i - gg * 24;
      const float* src = x + (b0 + gg) * 72 + tt * 3;
      float4 f; f.x = src[0]; f.y = src[1]; f.z = src[2]; f.w = 0.f;
      s_x4[gg][tt] = f;
    }
  }
  __syncthreads();

  // ================= ENCODER (+ inline w2d) =================
  // Input-attention constants prescaled: A1/A2 by K2L (tanh args in exp2 units),
  // A3/a3b by L2E (softmax exp becomes raw exp2).
  const float A1c0 = K2L * attn1_w[jj], A1c1 = K2L * attn1_w[16 + jj], A1c2 = K2L * attn1_w[32 + jj];
  const float a1b0 = K2L * attn1_b[0], a1b1 = K2L * attn1_b[1], a1b2 = K2L * attn1_b[2];
  float A2[9], A3[9];
#pragma unroll
  for (int i = 0; i < 9; ++i) { A2[i] = K2L * attn2_w[i]; A3[i] = L2E * attn3_w[i]; }
  const float a2b0 = K2L * attn2_b[0], a2b1 = K2L * attn2_b[1], a2b2 = K2L * attn2_b[2];
  const float a3b0 = L2E * attn3_b[0], a3b1 = L2E * attn3_b[1], a3b2 = L2E * attn3_b[2];
  float WI[3][3];
#pragma unroll
  for (int c = 0; c < 3; ++c)
#pragma unroll
    for (int i = 0; i < 3; ++i) WI[c][i] = enc_wih[(c * 16 + jj) * 3 + i];
  const float BI0 = enc_bih[jj], BI1 = enc_bih[16 + jj], BI2 = enc_bih[32 + jj];
  v2f WHr[8], WHz[8], WHn[8];
#pragma unroll
  for (int k = 0; k < 8; ++k) {
    WHr[k] = v2(enc_whh[jj * 16 + 2 * k], enc_whh[jj * 16 + 2 * k + 1]);
    WHz[k] = v2(enc_whh[(16 + jj) * 16 + 2 * k], enc_whh[(16 + jj) * 16 + 2 * k + 1]);
    WHn[k] = v2(enc_whh[(32 + jj) * 16 + 2 * k], enc_whh[(32 + jj) * 16 + 2 * k + 1]);
  }
  const float BH0 = enc_bhh[jj], BH1 = enc_bhh[16 + jj], BH2 = enc_bhh[32 + jj];
  const v2f l2bv = v2(K2L * l2_b[j0], K2L * l2_b[j1]);

  float h = h0_enc[b * 16 + jj];
  float enc_reg[NT];
  v2f w2dv[NT];  // K2L-scaled

  s_bc[g][jj] = h;
  creg_fence();

#pragma unroll
  for (int t = 0; t < NT; ++t) {
    const float4 xq = s_x4[g][t];
    const float xs0 = xq.x, xs1 = xq.y, xs2 = xq.z;
    // input-attention: shared-rcp tanh trio + exp2 softmax (max-free, |v| bounded)
    const float w10 = dpp16_sum(h * A1c0) + a1b0;
    const float w11 = dpp16_sum(h * A1c1) + a1b1;
    const float w12 = dpp16_sum(h * A1c2) + a1b2;
    const float w20 = a2b0 + xs0 * A2[0] + xs1 * A2[1] + xs2 * A2[2];
    const float w21 = a2b1 + xs0 * A2[3] + xs1 * A2[4] + xs2 * A2[5];
    const float w22 = a2b2 + xs0 * A2[6] + xs1 * A2[7] + xs2 * A2[8];
    const float Aa = 1.f + exp2_fast(w10 + w20);
    const float Ab = 1.f + exp2_fast(w11 + w21);
    const float Ac = 1.f + exp2_fast(w12 + w22);
    const float Pab = Aa * Ab;
    const float r3 = rcp_fast(Pab * Ac);
    const float tc2 = Pab * r3;           // 1/Ac
    const float tAc = Ac * r3;
    const float ta2 = Ab * tAc;           // 1/Aa
    const float tb2 = Aa * tAc;           // 1/Ab
    const float t0 = 1.f - 2.f * ta2, t1 = 1.f - 2.f * tb2, t2 = 1.f - 2.f * tc2;
    const float v0 = a3b0 + t0 * A3[0] + t1 * A3[1] + t2 * A3[2];
    const float v1 = a3b1 + t0 * A3[3] + t1 * A3[4] + t2 * A3[5];
    const float v2_ = a3b2 + t0 * A3[6] + t1 * A3[7] + t2 * A3[8];
    const float e0 = exp2_fast(v0), e1 = exp2_fast(v1), e2 = exp2_fast(v2_);
    const float rs = rcp_fast(e0 + e1 + e2);
    const float wx0 = xs0 * e0 * rs, wx1 = xs1 * e1 * rs, wx2 = xs2 * e2 * rs;
    // GRU cell (packed whh), reads h_{t-1} broadcast from s_bc
    const float gir = BI0 + wx0 * WI[0][0] + wx1 * WI[0][1] + wx2 * WI[0][2];
    const float giz = BI1 + wx0 * WI[1][0] + wx1 * WI[1][1] + wx2 * WI[1][2];
    const float gin = BI2 + wx0 * WI[2][0] + wx1 * WI[2][1] + wx2 * WI[2][2];
    v2f ar = v2s(0.f), az = v2s(0.f), an = v2s(0.f);
#pragma unroll
    for (int kk = 0; kk < 4; ++kk) {
      const float4 hq = *(const float4*)&s_bc[g][4 * kk];
      const v2f hp0 = v2(hq.x, hq.y), hp1 = v2(hq.z, hq.w);
      ar = v2fma(hp0, WHr[2 * kk], ar); ar = v2fma(hp1, WHr[2 * kk + 1], ar);
      az = v2fma(hp0, WHz[2 * kk], az); az = v2fma(hp1, WHz[2 * kk + 1], az);
      an = v2fma(hp0, WHn[2 * kk], an); an = v2fma(hp1, WHn[2 * kk + 1], an);
    }
    const float ghr = BH0 + ar.x + ar.y;
    const float ghz = BH1 + az.x + az.y;
    const float ghn = BH2 + an.x + an.y;
    const float r = sigmoid_f(gir + ghr);
    const float z = sigmoid_f(giz + ghz);
    const float n = tanh_f(gin + r * ghn);
    h = n + z * (h - n);
    enc_reg[t] = h;
    s_bc[g][jj] = h;
    creg_fence();
    // w2d[t] = l2(enc[t]) packed over (j0,j1), K2L-scaled
    v2f w2t = l2bv;
#pragma unroll
    for (int kk = 0; kk < 4; ++kk) {
      const float4 hq = *(const float4*)&s_bc[g][4 * kk];
      const float4 f0 = s_l2w4[(2 * kk) * 16 + jj];
      const float4 f1 = s_l2w4[(2 * kk + 1) * 16 + jj];
      w2t = v2fma(v2s(hq.x), v2(f0.x, f0.y), w2t);
      w2t = v2fma(v2s(hq.y), v2(f0.z, f0.w), w2t);
      w2t = v2fma(v2s(hq.z), v2(f1.x, f1.y), w2t);
      w2t = v2fma(v2s(hq.w), v2(f1.z, f1.w), w2t);
    }
    w2dv[t] = w2t;
  }

  // ================= DECODER =================
  // M-tile into registers (one-time; static indices, fully unrolled uses)
  float4 rm[24];
#pragma unroll
  for (int i = 0; i < 24; ++i) rm[i] = s_m4[i * 16 + jj];

  const v2f l1bv = v2(K2L * l1_b[j0], K2L * l1_b[j1]);
  // attention weights folded: m3 = -2*log2e*l3 -> score comes out in exp2 units
  const v2f m3v = v2(-2.f * L2E * l3_w[j0], -2.f * L2E * l3_w[j1]);
  const v2f dhrv = v2(dec_bhh[j0], dec_bhh[j1]);
  const v2f dhzv = v2(dec_bhh[32 + j0], dec_bhh[32 + j1]);
  const v2f dhnv = v2(dec_bhh[64 + j0], dec_bhh[64 + j1]);
  const float4 cr0 = s_cmx[j0], cr1 = s_cmx[j1];
  const float4 cz0 = s_cmx[32 + j0], cz1 = s_cmx[32 + j1];
  const float4 cn0 = s_cmx[64 + j0], cn1 = s_cmx[64 + j1];
  const v2f crc = v2(cr0.x, cr1.x), crx0 = v2(cr0.y, cr1.y), crx1 = v2(cr0.z, cr1.z), crx2 = v2(cr0.w, cr1.w);
  const v2f czc = v2(cz0.x, cz1.x), czx0 = v2(cz0.y, cz1.y), czx1 = v2(cz0.z, cz1.z), czx2 = v2(cz0.w, cz1.w);
  const v2f cnc = v2(cn0.x, cn1.x), cnx0 = v2(cn0.y, cn1.y), cnx1 = v2(cn0.z, cn1.z), cnx2 = v2(cn0.w, cn1.w);

  float hd0 = h0_dec[b * 32 + j0], hd1 = h0_dec[b * 32 + j1];

  for (int t = 0; t < NT; ++t) {
    const float4 xq = s_x4[g][t];

    s_bc[g][jj] = hd0;
    s_bc[g][16 + jj] = hd1;
    creg_fence();

    // --- w1 = l1(hd) (K2L-scaled) and gh = dec_whh @ hd ---
    v2f w1v = l1bv;
    v2f hrv = dhrv, hzv = dhzv, hnv = dhnv;
#pragma unroll
    for (int kk = 0; kk < 8; ++kk) {
      const float4 hq = *(const float4*)&s_bc[g][4 * kk];
      const float4 f0 = s_l1w4[(2 * kk) * 16 + jj];
      const float4 f1 = s_l1w4[(2 * kk + 1) * 16 + jj];
      w1v = v2fma(v2s(hq.x), v2(f0.x, f0.y), w1v);
      w1v = v2fma(v2s(hq.y), v2(f0.z, f0.w), w1v);
      w1v = v2fma(v2s(hq.z), v2(f1.x, f1.y), w1v);
      w1v = v2fma(v2s(hq.w), v2(f1.z, f1.w), w1v);
      GATE_PK16(s_dwhh4, hq, kk, hrv, hzv, hnv);
    }

    // --- temporal attention: paired-rcp tanh + exp2 score, max-free
    //     (score bounded by 2*sum|l3| ~ 5; constant term cancels in the ratio) ---
    float ssum0 = 0.f, ssum1 = 0.f, wca0 = 0.f, wca1 = 0.f;
#pragma unroll
    for (int ch = 0; ch < 6; ++ch) {
      float p[4];
#pragma unroll
      for (int u = 0; u < 4; ++u) {
        const v2f av = w1v + w2dv[4 * ch + u];   // exp2-units of 2*(w1+w2d)
        const float Ax = 1.f + exp2_fast(av.x);
        const float Ay = 1.f + exp2_fast(av.y);
        const float rr = rcp_fast(Ax * Ay);
        float uu = m3v.x * Ay;
        uu = fmaf(m3v.y, Ax, uu);
        p[u] = exp2_fast(dpp16_sum(uu * rr));
      }
      ssum0 += p[0] + p[1];
      ssum1 += p[2] + p[3];
      wca0 += p[0] * enc_reg[4 * ch] + p[1] * enc_reg[4 * ch + 1];
      wca1 += p[2] * enc_reg[4 * ch + 2] + p[3] * enc_reg[4 * ch + 3];
    }
    const float wc = (wca0 + wca1) * rcp_fast(ssum0 + ssum1);

    // --- gi = c0 + MX@x + M@wc  (M in registers) ---
    s_bc[g][jj] = wc;
    creg_fence();
    v2f irv = crc, izv = czc, inv = cnc;
    irv = v2fma(v2s(xq.x), crx0, irv); irv = v2fma(v2s(xq.y), crx1, irv); irv = v2fma(v2s(xq.z), crx2, irv);
    izv = v2fma(v2s(xq.x), czx0, izv); izv = v2fma(v2s(xq.y), czx1, izv); izv = v2fma(v2s(xq.z), czx2, izv);
    inv = v2fma(v2s(xq.x), cnx0, inv); inv = v2fma(v2s(xq.y), cnx1, inv); inv = v2fma(v2s(xq.z), cnx2, inv);
#pragma unroll
    for (int kk = 0; kk < 4; ++kk) {
      const float4 cq = *(const float4*)&s_bc[g][4 * kk];
      GATE_PK8R(cq, kk, irv, izv, inv);
    }

    const float r0 = sigmoid_f(irv.x + hrv.x), r1 = sigmoid_f(irv.y + hrv.y);
    const float z0 = sigmoid_f(izv.x + hzv.x), z1 = sigmoid_f(izv.y + hzv.y);
    const float n0 = tanh_f(inv.x + r0 * hnv.x), n1 = tanh_f(inv.y + r1 * hnv.y);
    hd0 = n0 + z0 * (hd0 - n0);
    hd1 = n1 + z1 * (hd1 - n1);
  }

  // ---- final fc ----
  const float p0 = dpp16_sum(hd0 * fc_w[jj] + hd1 * fc_w[16 + jj]) + fc_b[0];
  const float p1 = dpp16_sum(hd0 * fc_w[32 + jj] + hd1 * fc_w[48 + jj]) + fc_b[1];
  const float p2 = dpp16_sum(hd0 * fc_w[64 + jj] + hd1 * fc_w[80 + jj]) + fc_b[2];
  if (jj == 0) {
    out[b * 3 + 0] = p0;
    out[b * 3 + 1] = p1;
    out[b * 3 + 2] = p2;
  }
}

extern "C" void kernel_launch(void* const* d_in, const int* in_sizes, int n_in,
                              void* d_out, int out_size, void* d_ws, size_t ws_size,
                              hipStream_t stream) {
  const float* p[27];
  for (int i = 0; i < 27; ++i) p[i] = (const float*)d_in[i];
  darnn_kernel<<<NB / 16, 256, 0, stream>>>(
      p[0], p[1], p[2], p[3], p[4], p[5], p[6], p[7], p[8],
      p[9], p[10], p[11], p[12], p[13], p[14], p[15], p[16], p[17], p[18],
      p[19], p[20], p[21], p[22], p[23], p[24], p[25], p[26],
      (float*)d_out);
}

// Round 8
// 120.533 us; speedup vs baseline: 6.0443x; 1.0132x over previous
//
#include <hip/hip_runtime.h>

#define NB 8192
#define NT 24

typedef float v2f __attribute__((ext_vector_type(2)));

#define K2L 2.8853900817779268f  // 2*log2(e)
#define L2E 1.4426950408889634f  // log2(e)

__device__ __forceinline__ float rcp_fast(float x) { return __builtin_amdgcn_rcpf(x); }
__device__ __forceinline__ float exp2_fast(float x) { return __builtin_amdgcn_exp2f(x); }
__device__ __forceinline__ float sigmoid_f(float x) { return rcp_fast(1.f + exp2_fast(-L2E * x)); }
__device__ __forceinline__ float tanh_f(float x) { return 1.f - 2.f * rcp_fast(1.f + exp2_fast(K2L * x)); }
// Compiler-only scheduling/live-range barrier (R4: removing it exploded regs into
// scratch; R6: hardware drain vs this = identical perf, so keep the free version).
__device__ __forceinline__ void creg_fence() { asm volatile("" ::: "memory"); }
__device__ __forceinline__ v2f v2(float a, float b) { v2f r; r.x = a; r.y = b; return r; }
__device__ __forceinline__ v2f v2s(float a) { v2f r; r.x = a; r.y = a; return r; }
__device__ __forceinline__ v2f v2fma(v2f a, v2f b, v2f c) { return __builtin_elementwise_fma(a, b, c); }

// Full sum across the 16 contiguous lanes of a group (groups aligned to 16).
__device__ __forceinline__ float dpp16_sum(float x) {
  int v;
  v = __builtin_amdgcn_update_dpp(0, __float_as_int(x), 0xB1, 0xF, 0xF, true);  // quad_perm(1,0,3,2)
  x += __int_as_float(v);
  v = __builtin_amdgcn_update_dpp(0, __float_as_int(x), 0x4E, 0xF, 0xF, true);  // quad_perm(2,3,0,1)
  x += __int_as_float(v);
  v = __builtin_amdgcn_update_dpp(0, __float_as_int(x), 0x141, 0xF, 0xF, true); // ROW_HALF_MIRROR
  x += __int_as_float(v);
  v = __builtin_amdgcn_update_dpp(0, __float_as_int(x), 0x140, 0xF, 0xF, true); // ROW_MIRROR
  x += __int_as_float(v);
  return x;
}

// 3 packed gate accumulators vs [96][32] pair-interleaved LDS tile (16 col-pairs/gate).
#define GATE_PK16(T, hq, kk, gr, gz, gn)                        \
  do {                                                          \
    const float4 a0 = T[(0 * 16 + 2 * (kk)) * 16 + jj];         \
    const float4 a1 = T[(0 * 16 + 2 * (kk) + 1) * 16 + jj];     \
    const float4 b0 = T[(1 * 16 + 2 * (kk)) * 16 + jj];         \
    const float4 b1 = T[(1 * 16 + 2 * (kk) + 1) * 16 + jj];     \
    const float4 c0 = T[(2 * 16 + 2 * (kk)) * 16 + jj];         \
    const float4 c1 = T[(2 * 16 + 2 * (kk) + 1) * 16 + jj];     \
    gr = v2fma(v2s(hq.x), v2(a0.x, a0.y), gr);                  \
    gr = v2fma(v2s(hq.y), v2(a0.z, a0.w), gr);                  \
    gr = v2fma(v2s(hq.z), v2(a1.x, a1.y), gr);                  \
    gr = v2fma(v2s(hq.w), v2(a1.z, a1.w), gr);                  \
    gz = v2fma(v2s(hq.x), v2(b0.x, b0.y), gz);                  \
    gz = v2fma(v2s(hq.y), v2(b0.z, b0.w), gz);                  \
    gz = v2fma(v2s(hq.z), v2(b1.x, b1.y), gz);                  \
    gz = v2fma(v2s(hq.w), v2(b1.z, b1.w), gz);                  \
    gn = v2fma(v2s(hq.x), v2(c0.x, c0.y), gn);                  \
    gn = v2fma(v2s(hq.y), v2(c0.z, c0.w), gn);                  \
    gn = v2fma(v2s(hq.z), v2(c1.x, c1.y), gn);                  \
    gn = v2fma(v2s(hq.w), v2(c1.z, c1.w), gn);                  \
  } while (0)

// Folded-M gate block from REGISTER tile rm[24] (gate*8 + 2kk layout).
#define GATE_PK8R(hq, kk, gr, gz, gn)                           \
  do {                                                          \
    const float4 a0 = rm[0 * 8 + 2 * (kk)];                     \
    const float4 a1 = rm[0 * 8 + 2 * (kk) + 1];                 \
    const float4 b0 = rm[1 * 8 + 2 * (kk)];                     \
    const float4 b1 = rm[1 * 8 + 2 * (kk) + 1];                 \
    const float4 c0 = rm[2 * 8 + 2 * (kk)];                     \
    const float4 c1 = rm[2 * 8 + 2 * (kk) + 1];                 \
    gr = v2fma(v2s(hq.x), v2(a0.x, a0.y), gr);                  \
    gr = v2fma(v2s(hq.y), v2(a0.z, a0.w), gr);                  \
    gr = v2fma(v2s(hq.z), v2(a1.x, a1.y), gr);                  \
    gr = v2fma(v2s(hq.w), v2(a1.z, a1.w), gr);                  \
    gz = v2fma(v2s(hq.x), v2(b0.x, b0.y), gz);                  \
    gz = v2fma(v2s(hq.y), v2(b0.z, b0.w), gz);                  \
    gz = v2fma(v2s(hq.z), v2(b1.x, b1.y), gz);                  \
    gz = v2fma(v2s(hq.w), v2(b1.z, b1.w), gz);                  \
    gn = v2fma(v2s(hq.x), v2(c0.x, c0.y), gn);                  \
    gn = v2fma(v2s(hq.y), v2(c0.z, c0.w), gn);                  \
    gn = v2fma(v2s(hq.z), v2(c1.x, c1.y), gn);                  \
    gn = v2fma(v2s(hq.w), v2(c1.z, c1.w), gn);                  \
  } while (0)

__global__ __launch_bounds__(256, 2) void darnn_kernel(
    const float* __restrict__ x, const float* __restrict__ h0_enc, const float* __restrict__ h0_dec,
    const float* __restrict__ attn1_w, const float* __restrict__ attn1_b,
    const float* __restrict__ attn2_w, const float* __restrict__ attn2_b,
    const float* __restrict__ attn3_w, const float* __restrict__ attn3_b,
    const float* __restrict__ enc_wih, const float* __restrict__ enc_whh,
    const float* __restrict__ enc_bih, const float* __restrict__ enc_bhh,
    const float* __restrict__ l1_w, const float* __restrict__ l1_b,
    const float* __restrict__ l2_w, const float* __restrict__ l2_b,
    const float* __restrict__ l3_w, const float* __restrict__ l3_b,
    const float* __restrict__ l4_w, const float* __restrict__ l4_b,
    const float* __restrict__ dec_wih, const float* __restrict__ dec_whh,
    const float* __restrict__ dec_bih, const float* __restrict__ dec_bhh,
    const float* __restrict__ fc_w, const float* __restrict__ fc_b,
    float* __restrict__ out)
{
  __shared__ float4 s_dwhh4[768];   // 12 KB pair-interleaved dec_whh
  __shared__ float4 s_l1w4[256];    // 4 KB, pre-scaled by K2L (feeds attention only)
  __shared__ float4 s_l2w4[128];    // 2 KB, pre-scaled by K2L
  __shared__ float4 s_m4[384];      // 6 KB staging for register M-tile
  __shared__ float4 s_cmx[96];      // 1.5 KB: {c0_r, MX_r0, MX_r1, MX_r2}
  __shared__ float4 s_x4[16][24];   // 6 KB
  __shared__ float s_bc[16][48];    // broadcast buffer, stride 48

  const int tid = threadIdx.x;
  const int g = tid >> 4;
  const int jj = tid & 15;
  const int b = blockIdx.x * 16 + g;
  const int j0 = jj, j1 = jj + 16;

  // ---- stage tiles ----
  for (int i = tid; i < 768; i += 256) {
    const int q = i >> 8, cp = (i >> 4) & 15, j = i & 15;
    const int r0 = q * 32 + j, r1 = r0 + 16, c0 = 2 * cp;
    float4 f;
    f.x = dec_whh[r0 * 32 + c0]; f.y = dec_whh[r1 * 32 + c0];
    f.z = dec_whh[r0 * 32 + c0 + 1]; f.w = dec_whh[r1 * 32 + c0 + 1];
    s_dwhh4[i] = f;
  }
  {
    const int cp = tid >> 4, j = tid & 15, c0 = 2 * cp;  // exactly 256
    float4 f;  // K2L-prescaled: w1 comes out in exp2 units
    f.x = K2L * l1_w[j * 32 + c0]; f.y = K2L * l1_w[(j + 16) * 32 + c0];
    f.z = K2L * l1_w[j * 32 + c0 + 1]; f.w = K2L * l1_w[(j + 16) * 32 + c0 + 1];
    s_l1w4[tid] = f;
  }
  if (tid < 128) {
    const int cp = tid >> 4, j = tid & 15, c0 = 2 * cp;
    float4 e;  // K2L-prescaled: w2d in exp2 units
    e.x = K2L * l2_w[j * 16 + c0]; e.y = K2L * l2_w[(j + 16) * 16 + c0];
    e.z = K2L * l2_w[j * 16 + c0 + 1]; e.w = K2L * l2_w[(j + 16) * 16 + c0 + 1];
    s_l2w4[tid] = e;
  }
  // M = dec_wih @ l4_w[:, :16]  (pair-interleaved, 8 col-pairs per gate)
  for (int i = tid; i < 384; i += 256) {
    const int j = i & 15, t4 = i >> 4;
    const int q = t4 >> 3, cp = t4 & 7;
    const int r0 = q * 32 + j, r1 = r0 + 16, c0 = 2 * cp, c1 = c0 + 1;
    float4 f; f.x = 0.f; f.y = 0.f; f.z = 0.f; f.w = 0.f;
    for (int k = 0; k < 32; ++k) {
      const float w0 = dec_wih[r0 * 32 + k], w1 = dec_wih[r1 * 32 + k];
      const float lc0 = l4_w[k * 19 + c0], lc1 = l4_w[k * 19 + c1];
      f.x += w0 * lc0; f.y += w1 * lc0; f.z += w0 * lc1; f.w += w1 * lc1;
    }
    s_m4[i] = f;
  }
  // c0 = dec_bih + dec_wih @ l4_b ; MX = dec_wih @ l4_w[:, 16:19]
  for (int r = tid; r < 96; r += 256) {
    float c = dec_bih[r], m0 = 0.f, m1 = 0.f, m2 = 0.f;
    for (int k = 0; k < 32; ++k) {
      const float w = dec_wih[r * 32 + k];
      c += w * l4_b[k];
      m0 += w * l4_w[k * 19 + 16]; m1 += w * l4_w[k * 19 + 17]; m2 += w * l4_w[k * 19 + 18];
    }
    float4 f; f.x = c; f.y = m0; f.z = m1; f.w = m2;
    s_cmx[r] = f;
  }
  {
    const int b0 = blockIdx.x * 16;
    for (int i = tid; i < 16 * 24; i += 256) {
      const int gg = i / 24, tt = i - gg * 24;
      const float* src = x + (b0 + gg) * 72 + tt * 3;
      float4 f; f.x = src[0]; f.y = src[1]; f.z = src[2]; f.w = 0.f;
      s_x4[gg][tt] = f;
    }
  }
  __syncthreads();

  // ================= ENCODER (+ merged w2d) =================
  const float A1c0 = K2L * attn1_w[jj], A1c1 = K2L * attn1_w[16 + jj], A1c2 = K2L * attn1_w[32 + jj];
  const float a1b0 = K2L * attn1_b[0], a1b1 = K2L * attn1_b[1], a1b2 = K2L * attn1_b[2];
  float A2[9], A3[9];
#pragma unroll
  for (int i = 0; i < 9; ++i) { A2[i] = K2L * attn2_w[i]; A3[i] = L2E * attn3_w[i]; }
  const float a2b0 = K2L * attn2_b[0], a2b1 = K2L * attn2_b[1], a2b2 = K2L * attn2_b[2];
  const float a3b0 = L2E * attn3_b[0], a3b1 = L2E * attn3_b[1], a3b2 = L2E * attn3_b[2];
  float WI[3][3];
#pragma unroll
  for (int c = 0; c < 3; ++c)
#pragma unroll
    for (int i = 0; i < 3; ++i) WI[c][i] = enc_wih[(c * 16 + jj) * 3 + i];
  const float BI0 = enc_bih[jj], BI1 = enc_bih[16 + jj], BI2 = enc_bih[32 + jj];
  v2f WHr[8], WHz[8], WHn[8];
#pragma unroll
  for (int k = 0; k < 8; ++k) {
    WHr[k] = v2(enc_whh[jj * 16 + 2 * k], enc_whh[jj * 16 + 2 * k + 1]);
    WHz[k] = v2(enc_whh[(16 + jj) * 16 + 2 * k], enc_whh[(16 + jj) * 16 + 2 * k + 1]);
    WHn[k] = v2(enc_whh[(32 + jj) * 16 + 2 * k], enc_whh[(32 + jj) * 16 + 2 * k + 1]);
  }
  const float BH0 = enc_bhh[jj], BH1 = enc_bhh[16 + jj], BH2 = enc_bhh[32 + jj];
  const v2f l2bv = v2(K2L * l2_b[j0], K2L * l2_b[j1]);

  float h = h0_enc[b * 16 + jj];
  float enc_reg[NT];
  v2f w2dv[NT];  // K2L-scaled

  s_bc[g][jj] = h;  // invariant: s_bc holds h_{t-1} at loop top
  creg_fence();

#pragma unroll
  for (int t = 0; t < NT; ++t) {
    const float4 xq = s_x4[g][t];
    const float xs0 = xq.x, xs1 = xq.y, xs2 = xq.z;
    // input-attention: shared-rcp tanh trio + exp2 softmax (max-free, |v| bounded)
    const float w10 = dpp16_sum(h * A1c0) + a1b0;
    const float w11 = dpp16_sum(h * A1c1) + a1b1;
    const float w12 = dpp16_sum(h * A1c2) + a1b2;
    const float w20 = a2b0 + xs0 * A2[0] + xs1 * A2[1] + xs2 * A2[2];
    const float w21 = a2b1 + xs0 * A2[3] + xs1 * A2[4] + xs2 * A2[5];
    const float w22 = a2b2 + xs0 * A2[6] + xs1 * A2[7] + xs2 * A2[8];
    const float Aa = 1.f + exp2_fast(w10 + w20);
    const float Ab = 1.f + exp2_fast(w11 + w21);
    const float Ac = 1.f + exp2_fast(w12 + w22);
    const float Pab = Aa * Ab;
    const float r3 = rcp_fast(Pab * Ac);
    const float tc2 = Pab * r3;           // 1/Ac
    const float tAc = Ac * r3;
    const float ta2 = Ab * tAc;           // 1/Aa
    const float tb2 = Aa * tAc;           // 1/Ab
    const float t0 = 1.f - 2.f * ta2, t1 = 1.f - 2.f * tb2, t2 = 1.f - 2.f * tc2;
    const float v0 = a3b0 + t0 * A3[0] + t1 * A3[1] + t2 * A3[2];
    const float v1 = a3b1 + t0 * A3[3] + t1 * A3[4] + t2 * A3[5];
    const float v2_ = a3b2 + t0 * A3[6] + t1 * A3[7] + t2 * A3[8];
    const float e0 = exp2_fast(v0), e1 = exp2_fast(v1), e2 = exp2_fast(v2_);
    const float rs = rcp_fast(e0 + e1 + e2);
    const float wx0 = xs0 * e0 * rs, wx1 = xs1 * e1 * rs, wx2 = xs2 * e2 * rs;
    // GRU gi (tiny input matmul)
    const float gir = BI0 + wx0 * WI[0][0] + wx1 * WI[0][1] + wx2 * WI[0][2];
    const float giz = BI1 + wx0 * WI[1][0] + wx1 * WI[1][1] + wx2 * WI[1][2];
    const float gin = BI2 + wx0 * WI[2][0] + wx1 * WI[2][1] + wx2 * WI[2][2];
    // shared h_{t-1} broadcast reads feed BOTH whh matmul and w2d[t-1] = l2(h_{t-1})
    v2f ar = v2s(0.f), az = v2s(0.f), an = v2s(0.f);
    v2f w2t = l2bv;
#pragma unroll
    for (int kk = 0; kk < 4; ++kk) {
      const float4 hq = *(const float4*)&s_bc[g][4 * kk];
      const v2f hp0 = v2(hq.x, hq.y), hp1 = v2(hq.z, hq.w);
      ar = v2fma(hp0, WHr[2 * kk], ar); ar = v2fma(hp1, WHr[2 * kk + 1], ar);
      az = v2fma(hp0, WHz[2 * kk], az); az = v2fma(hp1, WHz[2 * kk + 1], az);
      an = v2fma(hp0, WHn[2 * kk], an); an = v2fma(hp1, WHn[2 * kk + 1], an);
      if (t > 0) {  // compile-time guard under unroll; t=0 h is h0 (not an output)
        const float4 f0 = s_l2w4[(2 * kk) * 16 + jj];
        const float4 f1 = s_l2w4[(2 * kk + 1) * 16 + jj];
        w2t = v2fma(v2s(hq.x), v2(f0.x, f0.y), w2t);
        w2t = v2fma(v2s(hq.y), v2(f0.z, f0.w), w2t);
        w2t = v2fma(v2s(hq.z), v2(f1.x, f1.y), w2t);
        w2t = v2fma(v2s(hq.w), v2(f1.z, f1.w), w2t);
      }
    }
    if (t > 0) w2dv[t - 1] = w2t;
    const float ghr = BH0 + ar.x + ar.y;
    const float ghz = BH1 + az.x + az.y;
    const float ghn = BH2 + an.x + an.y;
    const float r = sigmoid_f(gir + ghr);
    const float z = sigmoid_f(giz + ghz);
    const float n = tanh_f(gin + r * ghn);
    h = n + z * (h - n);
    enc_reg[t] = h;
    s_bc[g][jj] = h;
    creg_fence();
  }
  // epilogue: w2d[23] from the final encoder state (sitting in s_bc)
  {
    v2f w2t = l2bv;
#pragma unroll
    for (int kk = 0; kk < 4; ++kk) {
      const float4 hq = *(const float4*)&s_bc[g][4 * kk];
      const float4 f0 = s_l2w4[(2 * kk) * 16 + jj];
      const float4 f1 = s_l2w4[(2 * kk + 1) * 16 + jj];
      w2t = v2fma(v2s(hq.x), v2(f0.x, f0.y), w2t);
      w2t = v2fma(v2s(hq.y), v2(f0.z, f0.w), w2t);
      w2t = v2fma(v2s(hq.z), v2(f1.x, f1.y), w2t);
      w2t = v2fma(v2s(hq.w), v2(f1.z, f1.w), w2t);
    }
    w2dv[NT - 1] = w2t;
  }

  // ================= DECODER =================
  // M-tile into registers; the asm keep-alive makes the values opaque so the
  // compiler CANNOT rematerialize them as in-loop LDS reads (R7: VGPR=128
  // proved it was doing exactly that). Occupancy is grid-capped at 2 blocks/CU,
  // so VGPRs up to 256 are free.
  float4 rm[24];
#pragma unroll
  for (int i = 0; i < 24; ++i) rm[i] = s_m4[i * 16 + jj];
#pragma unroll
  for (int i = 0; i < 24; ++i)
    asm volatile("" : "+v"(rm[i].x), "+v"(rm[i].y), "+v"(rm[i].z), "+v"(rm[i].w));

  const v2f l1bv = v2(K2L * l1_b[j0], K2L * l1_b[j1]);
  const v2f m3v = v2(-2.f * L2E * l3_w[j0], -2.f * L2E * l3_w[j1]);
  const v2f dhrv = v2(dec_bhh[j0], dec_bhh[j1]);
  const v2f dhzv = v2(dec_bhh[32 + j0], dec_bhh[32 + j1]);
  const v2f dhnv = v2(dec_bhh[64 + j0], dec_bhh[64 + j1]);
  const float4 cr0 = s_cmx[j0], cr1 = s_cmx[j1];
  const float4 cz0 = s_cmx[32 + j0], cz1 = s_cmx[32 + j1];
  const float4 cn0 = s_cmx[64 + j0], cn1 = s_cmx[64 + j1];
  const v2f crc = v2(cr0.x, cr1.x), crx0 = v2(cr0.y, cr1.y), crx1 = v2(cr0.z, cr1.z), crx2 = v2(cr0.w, cr1.w);
  const v2f czc = v2(cz0.x, cz1.x), czx0 = v2(cz0.y, cz1.y), czx1 = v2(cz0.z, cz1.z), czx2 = v2(cz0.w, cz1.w);
  const v2f cnc = v2(cn0.x, cn1.x), cnx0 = v2(cn0.y, cn1.y), cnx1 = v2(cn0.z, cn1.z), cnx2 = v2(cn0.w, cn1.w);

  float hd0 = h0_dec[b * 32 + j0], hd1 = h0_dec[b * 32 + j1];

  for (int t = 0; t < NT; ++t) {
    const float4 xq = s_x4[g][t];

    s_bc[g][jj] = hd0;
    s_bc[g][16 + jj] = hd1;
    creg_fence();

    // --- w1 = l1(hd) (K2L-scaled) and gh = dec_whh @ hd ---
    v2f w1v = l1bv;
    v2f hrv = dhrv, hzv = dhzv, hnv = dhnv;
#pragma unroll
    for (int kk = 0; kk < 8; ++kk) {
      const float4 hq = *(const float4*)&s_bc[g][4 * kk];
      const float4 f0 = s_l1w4[(2 * kk) * 16 + jj];
      const float4 f1 = s_l1w4[(2 * kk + 1) * 16 + jj];
      w1v = v2fma(v2s(hq.x), v2(f0.x, f0.y), w1v);
      w1v = v2fma(v2s(hq.y), v2(f0.z, f0.w), w1v);
      w1v = v2fma(v2s(hq.z), v2(f1.x, f1.y), w1v);
      w1v = v2fma(v2s(hq.w), v2(f1.z, f1.w), w1v);
      GATE_PK16(s_dwhh4, hq, kk, hrv, hzv, hnv);
    }

    // --- temporal attention: paired-rcp tanh + exp2 score, max-free ---
    float ssum0 = 0.f, ssum1 = 0.f, wca0 = 0.f, wca1 = 0.f;
#pragma unroll
    for (int ch = 0; ch < 6; ++ch) {
      float p[4];
#pragma unroll
      for (int u = 0; u < 4; ++u) {
        const v2f av = w1v + w2dv[4 * ch + u];   // exp2-units of 2*(w1+w2d)
        const float Ax = 1.f + exp2_fast(av.x);
        const float Ay = 1.f + exp2_fast(av.y);
        const float rr = rcp_fast(Ax * Ay);
        float uu = m3v.x * Ay;
        uu = fmaf(m3v.y, Ax, uu);
        p[u] = exp2_fast(dpp16_sum(uu * rr));
      }
      ssum0 += p[0] + p[1];
      ssum1 += p[2] + p[3];
      wca0 += p[0] * enc_reg[4 * ch] + p[1] * enc_reg[4 * ch + 1];
      wca1 += p[2] * enc_reg[4 * ch + 2] + p[3] * enc_reg[4 * ch + 3];
    }
    const float wc = (wca0 + wca1) * rcp_fast(ssum0 + ssum1);

    // --- gi = c0 + MX@x + M@wc  (M in forced registers) ---
    s_bc[g][jj] = wc;
    creg_fence();
    v2f irv = crc, izv = czc, inv = cnc;
    irv = v2fma(v2s(xq.x), crx0, irv); irv = v2fma(v2s(xq.y), crx1, irv); irv = v2fma(v2s(xq.z), crx2, irv);
    izv = v2fma(v2s(xq.x), czx0, izv); izv = v2fma(v2s(xq.y), czx1, izv); izv = v2fma(v2s(xq.z), czx2, izv);
    inv = v2fma(v2s(xq.x), cnx0, inv); inv = v2fma(v2s(xq.y), cnx1, inv); inv = v2fma(v2s(xq.z), cnx2, inv);
#pragma unroll
    for (int kk = 0; kk < 4; ++kk) {
      const float4 cq = *(const float4*)&s_bc[g][4 * kk];
      GATE_PK8R(cq, kk, irv, izv, inv);
    }

    const float r0 = sigmoid_f(irv.x + hrv.x), r1 = sigmoid_f(irv.y + hrv.y);
    const float z0 = sigmoid_f(izv.x + hzv.x), z1 = sigmoid_f(izv.y + hzv.y);
    const float n0 = tanh_f(inv.x + r0 * hnv.x), n1 = tanh_f(inv.y + r1 * hnv.y);
    hd0 = n0 + z0 * (hd0 - n0);
    hd1 = n1 + z1 * (hd1 - n1);
  }

  // ---- final fc ----
  const float p0 = dpp16_sum(hd0 * fc_w[jj] + hd1 * fc_w[16 + jj]) + fc_b[0];
  const float p1 = dpp16_sum(hd0 * fc_w[32 + jj] + hd1 * fc_w[48 + jj]) + fc_b[1];
  const float p2 = dpp16_sum(hd0 * fc_w[64 + jj] + hd1 * fc_w[80 + jj]) + fc_b[2];
  if (jj == 0) {
    out[b * 3 + 0] = p0;
    out[b * 3 + 1] = p1;
    out[b * 3 + 2] = p2;
  }
}

extern "C" void kernel_launch(void* const* d_in, const int* in_sizes, int n_in,
                              void* d_out, int out_size, void* d_ws, size_t ws_size,
                              hipStream_t stream) {
  const float* p[27];
  for (int i = 0; i < 27; ++i) p[i] = (const float*)d_in[i];
  darnn_kernel<<<NB / 16, 256, 0, stream>>>(
      p[0], p[1], p[2], p[3], p[4], p[5], p[6], p[7], p[8],
      p[9], p[10], p[11], p[12], p[13], p[14], p[15], p[16], p[17], p[18],
      p[19], p[20], p[21], p[22], p[23], p[24], p[25], p[26],
      (float*)d_out);
}